// Round 1
// baseline (1357.557 us; speedup 1.0000x reference)
//
#include <hip/hip_runtime.h>
#include <math.h>

// Problem constants: B=1, H=W=64 (N=4096), C=768, 12 heads x hd=64.
#define NHEADS 12
#define NTOK 4096
#define CDIM 768

// ---------------------------------------------------------------------------
// QKV GEMM: x[4096,768] @ w[768,2304] + b, scattered to q/k/v [12][4096][64]
// 64x64 tile, BK=16, 256 threads, 4x4 micro-tile per thread.
// ---------------------------------------------------------------------------
__global__ __launch_bounds__(256) void qkv_gemm_kernel(
    const float* __restrict__ x, const float* __restrict__ w,
    const float* __restrict__ bias, float* __restrict__ qb,
    float* __restrict__ kb, float* __restrict__ vb)
{
    __shared__ __align__(16) float As[16][64];  // As[k][m]
    __shared__ __align__(16) float Bs[16][64];  // Bs[k][n]
    const int t = threadIdx.x;
    const int row0 = blockIdx.y * 64;
    const int col0 = blockIdx.x * 64;
    const int tm = (t >> 4) << 2;
    const int tn = (t & 15) << 2;
    const int lm  = t >> 2;          // A-load row
    const int lk  = (t & 3) << 2;    // A-load col offset
    const int lbr = t >> 4;          // B-load row
    const int lbc = (t & 15) << 2;   // B-load col
    float acc[4][4] = {};
    for (int kk = 0; kk < 768; kk += 16) {
        float4 av = *reinterpret_cast<const float4*>(
            x + (size_t)(row0 + lm) * 768 + kk + lk);
        float4 bv = *reinterpret_cast<const float4*>(
            w + (size_t)(kk + lbr) * 2304 + col0 + lbc);
        As[lk + 0][lm] = av.x; As[lk + 1][lm] = av.y;
        As[lk + 2][lm] = av.z; As[lk + 3][lm] = av.w;
        *reinterpret_cast<float4*>(&Bs[lbr][lbc]) = bv;
        __syncthreads();
#pragma unroll
        for (int kq = 0; kq < 16; ++kq) {
            float4 a4 = *reinterpret_cast<const float4*>(&As[kq][tm]);
            float4 b4 = *reinterpret_cast<const float4*>(&Bs[kq][tn]);
            float a[4] = {a4.x, a4.y, a4.z, a4.w};
            float b[4] = {b4.x, b4.y, b4.z, b4.w};
#pragma unroll
            for (int ii = 0; ii < 4; ++ii)
#pragma unroll
                for (int jj = 0; jj < 4; ++jj)
                    acc[ii][jj] = fmaf(a[ii], b[jj], acc[ii][jj]);
        }
        __syncthreads();
    }
    // epilogue: col j = s*768 + h*64 + d  ->  {q,k,v}[h][row][d]
#pragma unroll
    for (int ii = 0; ii < 4; ++ii) {
#pragma unroll
        for (int jj = 0; jj < 4; ++jj) {
            const int j = col0 + tn + jj;
            const float val = acc[ii][jj] + bias[j];
            const int s = j / 768;
            const int r = j - s * 768;
            const int h = r >> 6;
            const int d = r & 63;
            float* dst = (s == 0) ? qb : (s == 1) ? kb : vb;
            dst[(size_t)(h * NTOK + row0 + tm + ii) * 64 + d] = val;
        }
    }
}

// ---------------------------------------------------------------------------
// Decomposed rel-pos projections:
//   relH[head][n][kh] = sum_d q[head][n][d] * rel_pos_h[qh-kh+63][d]
//   relW[head][n][kw] = sum_d q[head][n][d] * rel_pos_w[qw-kw+63][d]
// one 64-thread block per (head,n); thread t = kh (resp. kw).
// ---------------------------------------------------------------------------
__global__ __launch_bounds__(64) void rel_kernel(
    const float* __restrict__ q, const float* __restrict__ rph,
    const float* __restrict__ rpw, float* __restrict__ relH,
    float* __restrict__ relW)
{
    __shared__ __align__(16) float qs[64];
    const int b = blockIdx.x;          // head*4096 + n
    const int t = threadIdx.x;
    const int n = b & 4095;
    const int qh = n >> 6;
    const int qw = n & 63;
    qs[t] = q[(size_t)b * 64 + t];
    __syncthreads();
    const float* rh = rph + (size_t)(qh - t + 63) * 64;
    const float* rw = rpw + (size_t)(qw - t + 63) * 64;
    float sh = 0.f, sw = 0.f;
#pragma unroll
    for (int d = 0; d < 64; d += 4) {
        float4 q4 = *reinterpret_cast<const float4*>(&qs[d]);
        float4 h4 = *reinterpret_cast<const float4*>(rh + d);
        float4 w4 = *reinterpret_cast<const float4*>(rw + d);
        sh += q4.x * h4.x + q4.y * h4.y + q4.z * h4.z + q4.w * h4.w;
        sw += q4.x * w4.x + q4.y * w4.y + q4.z * w4.z + q4.w * w4.w;
    }
    relH[(size_t)b * 64 + t] = sh;
    relW[(size_t)b * 64 + t] = sw;
}

// ---------------------------------------------------------------------------
// Flash attention per (head, q-tile of 64 rows). TK=64.
// S[r][j] = scale*q.k + relH[row][kt] + relW[row][j]; online softmax; O += P.V
// LDS exactly 64KB: QsT/KsT (d-major), Vs, Ps (row-major).
// Thread (g=t>>4, u=t&15) owns rows r0=4g, cols c0=4u (both S and O tiles).
// ---------------------------------------------------------------------------
__global__ __launch_bounds__(256) void flash_kernel(
    const float* __restrict__ qb, const float* __restrict__ kb,
    const float* __restrict__ vb, const float* __restrict__ relH,
    const float* __restrict__ relW, float* __restrict__ ao)
{
    __shared__ __align__(16) float QsT[64][64];  // [d][r], pre-scaled
    __shared__ __align__(16) float KsT[64][64];  // [d][j]
    __shared__ __align__(16) float Vs[64][64];   // [j][c]
    __shared__ __align__(16) float Ps[64][64];   // [r][j]

    const int t = threadIdx.x;
    const int qt = blockIdx.x;
    const int head = blockIdx.y;
    const int row0 = qt * 64;
    const size_t headBase = (size_t)head * NTOK * 64;
    const float scale = 0.125f;  // hd^-0.5, hd=64

    // stage Q tile transposed + scaled
    {
        const int r = t >> 2;
        const int d0 = (t & 3) * 16;
        const float* src = qb + headBase + (size_t)(row0 + r) * 64 + d0;
#pragma unroll
        for (int i = 0; i < 4; ++i) {
            float4 v4 = *reinterpret_cast<const float4*>(src + 4 * i);
            QsT[d0 + 4 * i + 0][r] = v4.x * scale;
            QsT[d0 + 4 * i + 1][r] = v4.y * scale;
            QsT[d0 + 4 * i + 2][r] = v4.z * scale;
            QsT[d0 + 4 * i + 3][r] = v4.w * scale;
        }
    }

    const int g = t >> 4;
    const int u = t & 15;
    const int r0 = g * 4;
    const int c0 = u * 4;

    float O[4][4] = {};
    float m_run[4] = {-1e30f, -1e30f, -1e30f, -1e30f};
    float l_run[4] = {};

    for (int kt = 0; kt < 64; ++kt) {
        __syncthreads();  // previous tile's consumers done (Q staging at kt=0)
        // stage K (transposed) and V tiles
        {
            const int j = t >> 2;
            const int d0 = (t & 3) * 16;
            const float* ksrc = kb + headBase + (size_t)(kt * 64 + j) * 64 + d0;
#pragma unroll
            for (int i = 0; i < 4; ++i) {
                float4 v4 = *reinterpret_cast<const float4*>(ksrc + 4 * i);
                KsT[d0 + 4 * i + 0][j] = v4.x;
                KsT[d0 + 4 * i + 1][j] = v4.y;
                KsT[d0 + 4 * i + 2][j] = v4.z;
                KsT[d0 + 4 * i + 3][j] = v4.w;
            }
            const float* vsrc = vb + headBase + (size_t)(kt * 64 + j) * 64 + d0;
#pragma unroll
            for (int i = 0; i < 4; ++i)
                *reinterpret_cast<float4*>(&Vs[j][d0 + 4 * i]) =
                    *reinterpret_cast<const float4*>(vsrc + 4 * i);
        }
        __syncthreads();

        // S = (scale*Q) K^T, 4x4 outer-product per thread
        float acc[4][4] = {};
#pragma unroll 8
        for (int d = 0; d < 64; ++d) {
            float4 a4 = *reinterpret_cast<const float4*>(&QsT[d][r0]);
            float4 b4 = *reinterpret_cast<const float4*>(&KsT[d][c0]);
            float a[4] = {a4.x, a4.y, a4.z, a4.w};
            float b[4] = {b4.x, b4.y, b4.z, b4.w};
#pragma unroll
            for (int ii = 0; ii < 4; ++ii)
#pragma unroll
                for (int jj = 0; jj < 4; ++jj)
                    acc[ii][jj] = fmaf(a[ii], b[jj], acc[ii][jj]);
        }
        // bias: kh = kt fixed for this tile; kw = column index (L1-resident)
#pragma unroll
        for (int ii = 0; ii < 4; ++ii) {
            const size_t rowoff = headBase + (size_t)(row0 + r0 + ii) * 64;
            const float hb = relH[rowoff + kt];
            float4 w4 = *reinterpret_cast<const float4*>(relW + rowoff + c0);
            acc[ii][0] += hb + w4.x;
            acc[ii][1] += hb + w4.y;
            acc[ii][2] += hb + w4.z;
            acc[ii][3] += hb + w4.w;
        }
        // online softmax: rows r0..r0+3 are owned by the 16 consecutive lanes
        // of group g -> 16-lane butterfly reductions
        float mt[4], alpha[4], srow[4];
#pragma unroll
        for (int ii = 0; ii < 4; ++ii)
            mt[ii] = fmaxf(fmaxf(acc[ii][0], acc[ii][1]),
                           fmaxf(acc[ii][2], acc[ii][3]));
#pragma unroll
        for (int off = 1; off < 16; off <<= 1)
#pragma unroll
            for (int ii = 0; ii < 4; ++ii)
                mt[ii] = fmaxf(mt[ii], __shfl_xor(mt[ii], off, 64));
#pragma unroll
        for (int ii = 0; ii < 4; ++ii) {
            const float mnew = fmaxf(m_run[ii], mt[ii]);
            alpha[ii] = __expf(m_run[ii] - mnew);
            m_run[ii] = mnew;
            srow[ii] = 0.f;
        }
#pragma unroll
        for (int ii = 0; ii < 4; ++ii)
#pragma unroll
            for (int jj = 0; jj < 4; ++jj) {
                const float p = __expf(acc[ii][jj] - m_run[ii]);
                acc[ii][jj] = p;
                srow[ii] += p;
            }
#pragma unroll
        for (int off = 1; off < 16; off <<= 1)
#pragma unroll
            for (int ii = 0; ii < 4; ++ii)
                srow[ii] += __shfl_xor(srow[ii], off, 64);
#pragma unroll
        for (int ii = 0; ii < 4; ++ii)
            l_run[ii] = l_run[ii] * alpha[ii] + srow[ii];
        // publish P (row-major, contiguous float4 per thread)
#pragma unroll
        for (int ii = 0; ii < 4; ++ii) {
            float4 p4 = {acc[ii][0], acc[ii][1], acc[ii][2], acc[ii][3]};
            *reinterpret_cast<float4*>(&Ps[r0 + ii][c0]) = p4;
        }
        __syncthreads();  // safety: P visible block-wide before PV
        // rescale O, then O += P.V
#pragma unroll
        for (int ii = 0; ii < 4; ++ii)
#pragma unroll
            for (int jj = 0; jj < 4; ++jj)
                O[ii][jj] *= alpha[ii];
#pragma unroll 4
        for (int j4 = 0; j4 < 64; j4 += 4) {
            float pr[4][4];
#pragma unroll
            for (int ii = 0; ii < 4; ++ii)
                *reinterpret_cast<float4*>(pr[ii]) =
                    *reinterpret_cast<const float4*>(&Ps[r0 + ii][j4]);
#pragma unroll
            for (int jo = 0; jo < 4; ++jo) {
                float4 v4 = *reinterpret_cast<const float4*>(&Vs[j4 + jo][c0]);
                float vv[4] = {v4.x, v4.y, v4.z, v4.w};
#pragma unroll
                for (int ii = 0; ii < 4; ++ii)
#pragma unroll
                    for (int jj = 0; jj < 4; ++jj)
                        O[ii][jj] = fmaf(pr[ii][jo], vv[jj], O[ii][jj]);
            }
        }
    }
    // epilogue: normalize and store head-major attention output
#pragma unroll
    for (int ii = 0; ii < 4; ++ii) {
        const float inv = 1.0f / l_run[ii];
        float4 o4 = {O[ii][0] * inv, O[ii][1] * inv, O[ii][2] * inv,
                     O[ii][3] * inv};
        *reinterpret_cast<float4*>(
            ao + headBase + (size_t)(row0 + r0 + ii) * 64 + c0) = o4;
    }
}

// ---------------------------------------------------------------------------
// Output projection: A[n][c] (c = h*64+d, gathered from head-major ao)
// @ proj_w[768,768] + proj_b -> out[4096,768]
// ---------------------------------------------------------------------------
__global__ __launch_bounds__(256) void proj_gemm_kernel(
    const float* __restrict__ ao, const float* __restrict__ w,
    const float* __restrict__ bias, float* __restrict__ out)
{
    __shared__ __align__(16) float As[16][64];
    __shared__ __align__(16) float Bs[16][64];
    const int t = threadIdx.x;
    const int row0 = blockIdx.y * 64;
    const int col0 = blockIdx.x * 64;
    const int tm = (t >> 4) << 2;
    const int tn = (t & 15) << 2;
    const int lm  = t >> 2;
    const int lk  = (t & 3) << 2;
    const int lbr = t >> 4;
    const int lbc = (t & 15) << 2;
    float acc[4][4] = {};
    for (int kk = 0; kk < 768; kk += 16) {
        const int c = kk + lk;  // 16-col span never crosses a 64-aligned head
        const int h = c >> 6;
        const int d = c & 63;
        float4 av = *reinterpret_cast<const float4*>(
            ao + ((size_t)h * NTOK + row0 + lm) * 64 + d);
        float4 bv = *reinterpret_cast<const float4*>(
            w + (size_t)(kk + lbr) * 768 + col0 + lbc);
        As[lk + 0][lm] = av.x; As[lk + 1][lm] = av.y;
        As[lk + 2][lm] = av.z; As[lk + 3][lm] = av.w;
        *reinterpret_cast<float4*>(&Bs[lbr][lbc]) = bv;
        __syncthreads();
#pragma unroll
        for (int kq = 0; kq < 16; ++kq) {
            float4 a4 = *reinterpret_cast<const float4*>(&As[kq][tm]);
            float4 b4 = *reinterpret_cast<const float4*>(&Bs[kq][tn]);
            float a[4] = {a4.x, a4.y, a4.z, a4.w};
            float b[4] = {b4.x, b4.y, b4.z, b4.w};
#pragma unroll
            for (int ii = 0; ii < 4; ++ii)
#pragma unroll
                for (int jj = 0; jj < 4; ++jj)
                    acc[ii][jj] = fmaf(a[ii], b[jj], acc[ii][jj]);
        }
        __syncthreads();
    }
#pragma unroll
    for (int ii = 0; ii < 4; ++ii)
#pragma unroll
        for (int jj = 0; jj < 4; ++jj)
            out[(size_t)(row0 + tm + ii) * 768 + col0 + tn + jj] =
                acc[ii][jj] + bias[col0 + tn + jj];
}

// ---------------------------------------------------------------------------
extern "C" void kernel_launch(void* const* d_in, const int* in_sizes, int n_in,
                              void* d_out, int out_size, void* d_ws,
                              size_t ws_size, hipStream_t stream)
{
    (void)in_sizes; (void)n_in; (void)out_size; (void)ws_size;
    const float* x    = (const float*)d_in[0];
    const float* qkvw = (const float*)d_in[1];
    const float* qkvb = (const float*)d_in[2];
    const float* pw   = (const float*)d_in[3];
    const float* pb   = (const float*)d_in[4];
    const float* rph  = (const float*)d_in[5];
    const float* rpw  = (const float*)d_in[6];
    float* out = (float*)d_out;
    float* ws  = (float*)d_ws;

    const size_t S = (size_t)NHEADS * NTOK * 64;  // 3.1M floats per buffer
    float* qb = ws;
    float* kb = ws + S;
    float* vb = ws + 2 * S;
    float* rH = ws + 3 * S;
    float* rW = ws + 4 * S;
    float* ao = ws + 5 * S;   // total ws use: 6*S*4B = 75.5 MB

    qkv_gemm_kernel<<<dim3(36, 64), 256, 0, stream>>>(x, qkvw, qkvb, qb, kb, vb);
    rel_kernel<<<dim3(NHEADS * NTOK), 64, 0, stream>>>(qb, rph, rpw, rH, rW);
    flash_kernel<<<dim3(64, NHEADS), 256, 0, stream>>>(qb, kb, vb, rH, rW, ao);
    proj_gemm_kernel<<<dim3(12, 64), 256, 0, stream>>>(ao, pw, pb, out);
}

// Round 2
// 587.482 us; speedup vs baseline: 2.3108x; 2.3108x over previous
//
#include <hip/hip_runtime.h>
#include <math.h>

// Problem constants: B=1, H=W=64 (N=4096), C=768, 12 heads x hd=64.
#define NHEADS 12
#define NTOK 4096

typedef __attribute__((ext_vector_type(8))) short bf8v;   // 8 x bf16 (4 VGPR)
typedef __attribute__((ext_vector_type(4))) float f4v;    // MFMA C/D frag

__device__ __forceinline__ unsigned short f2bf(float f) {
  unsigned int u = __float_as_uint(f);
  u += 0x7fffu + ((u >> 16) & 1u);   // RNE
  return (unsigned short)(u >> 16);
}
__device__ __forceinline__ float bf2f(unsigned short h) {
  return __uint_as_float(((unsigned int)h) << 16);
}
__device__ __forceinline__ bf8v pack8(float4 a, float4 b) {
  bf8v v;
  v[0] = (short)f2bf(a.x); v[1] = (short)f2bf(a.y);
  v[2] = (short)f2bf(a.z); v[3] = (short)f2bf(a.w);
  v[4] = (short)f2bf(b.x); v[5] = (short)f2bf(b.y);
  v[6] = (short)f2bf(b.z); v[7] = (short)f2bf(b.w);
  return v;
}

// DPP rotate within 16-lane rows (C-layout rows are 16 consecutive lanes)
template <int CTRL>
__device__ __forceinline__ float dppmov(float x) {
  return __int_as_float(__builtin_amdgcn_update_dpp(
      0, __float_as_int(x), CTRL, 0xf, 0xf, true));
}
__device__ __forceinline__ float rowmax16(float x) {
  x = fmaxf(x, dppmov<0x128>(x));  // row_ror:8
  x = fmaxf(x, dppmov<0x124>(x));  // row_ror:4
  x = fmaxf(x, dppmov<0x122>(x));  // row_ror:2
  x = fmaxf(x, dppmov<0x121>(x));  // row_ror:1
  return x;
}
__device__ __forceinline__ float rowsum16(float x) {
  x += dppmov<0x128>(x);
  x += dppmov<0x124>(x);
  x += dppmov<0x122>(x);
  x += dppmov<0x121>(x);
  return x;
}

// ---------------------------------------------------------------------------
// QKV GEMM: x[4096,768] @ w[768,2304] + b, scattered to q/k/v [12][4096][64]
// ---------------------------------------------------------------------------
__global__ __launch_bounds__(256) void qkv_gemm_kernel(
    const float* __restrict__ x, const float* __restrict__ w,
    const float* __restrict__ bias, float* __restrict__ qb,
    float* __restrict__ kb, float* __restrict__ vb)
{
    __shared__ __align__(16) float As[16][64];
    __shared__ __align__(16) float Bs[16][64];
    const int t = threadIdx.x;
    const int row0 = blockIdx.y * 64;
    const int col0 = blockIdx.x * 64;
    const int tm = (t >> 4) << 2;
    const int tn = (t & 15) << 2;
    const int lm  = t >> 2;
    const int lk  = (t & 3) << 2;
    const int lbr = t >> 4;
    const int lbc = (t & 15) << 2;
    float acc[4][4] = {};
    for (int kk = 0; kk < 768; kk += 16) {
        float4 av = *reinterpret_cast<const float4*>(
            x + (size_t)(row0 + lm) * 768 + kk + lk);
        float4 bv = *reinterpret_cast<const float4*>(
            w + (size_t)(kk + lbr) * 2304 + col0 + lbc);
        As[lk + 0][lm] = av.x; As[lk + 1][lm] = av.y;
        As[lk + 2][lm] = av.z; As[lk + 3][lm] = av.w;
        *reinterpret_cast<float4*>(&Bs[lbr][lbc]) = bv;
        __syncthreads();
#pragma unroll
        for (int kq = 0; kq < 16; ++kq) {
            float4 a4 = *reinterpret_cast<const float4*>(&As[kq][tm]);
            float4 b4 = *reinterpret_cast<const float4*>(&Bs[kq][tn]);
            float a[4] = {a4.x, a4.y, a4.z, a4.w};
            float b[4] = {b4.x, b4.y, b4.z, b4.w};
#pragma unroll
            for (int ii = 0; ii < 4; ++ii)
#pragma unroll
                for (int jj = 0; jj < 4; ++jj)
                    acc[ii][jj] = fmaf(a[ii], b[jj], acc[ii][jj]);
        }
        __syncthreads();
    }
#pragma unroll
    for (int ii = 0; ii < 4; ++ii) {
#pragma unroll
        for (int jj = 0; jj < 4; ++jj) {
            const int j = col0 + tn + jj;
            const float val = acc[ii][jj] + bias[j];
            const int s = j / 768;
            const int r = j - s * 768;
            const int h = r >> 6;
            const int d = r & 63;
            float* dst = (s == 0) ? qb : (s == 1) ? kb : vb;
            dst[(size_t)(h * NTOK + row0 + tm + ii) * 64 + d] = val;
        }
    }
}

// ---------------------------------------------------------------------------
// prepK: fp32 K -> bf16 K (same [h][tok][d] layout)
// ---------------------------------------------------------------------------
__global__ __launch_bounds__(256) void prepk_kernel(
    const float* __restrict__ kb, short* __restrict__ kbh)
{
    const int tt = blockIdx.x, h = blockIdx.y, t = threadIdx.x;
    const int tok = tt * 64 + (t >> 2);
    const int d0 = (t & 3) * 16;
    const float* src = kb + ((size_t)h * NTOK + tok) * 64 + d0;
    float4 a0 = *(const float4*)(src);
    float4 a1 = *(const float4*)(src + 4);
    float4 a2 = *(const float4*)(src + 8);
    float4 a3 = *(const float4*)(src + 12);
    short* dst = kbh + ((size_t)h * NTOK + tok) * 64 + d0;
    *(bf8v*)(dst) = pack8(a0, a1);
    *(bf8v*)(dst + 8) = pack8(a2, a3);
}

// ---------------------------------------------------------------------------
// prepV: fp32 V [h][tok][d] -> bf16 V^T [h][d][tok] via LDS transpose
// ---------------------------------------------------------------------------
__global__ __launch_bounds__(256) void prepv_kernel(
    const float* __restrict__ vb, short* __restrict__ vbT)
{
    __shared__ float Vsf[64][65];   // odd stride: conflict-free both sides
    const int tt = blockIdx.x, h = blockIdx.y, t = threadIdx.x;
    {
        const int tok = t >> 2, d0 = (t & 3) * 16;
        const float* src = vb + ((size_t)h * NTOK + tt * 64 + tok) * 64 + d0;
#pragma unroll
        for (int i = 0; i < 4; ++i) {
            float4 a = *(const float4*)(src + 4 * i);
            Vsf[tok][d0 + 4 * i + 0] = a.x;
            Vsf[tok][d0 + 4 * i + 1] = a.y;
            Vsf[tok][d0 + 4 * i + 2] = a.z;
            Vsf[tok][d0 + 4 * i + 3] = a.w;
        }
    }
    __syncthreads();
#pragma unroll
    for (int p = 0; p < 2; ++p) {
        const int d = (t >> 3) + 32 * p;
        const int tk0 = (t & 7) * 8;
        bf8v v;
#pragma unroll
        for (int i = 0; i < 8; ++i) v[i] = (short)f2bf(Vsf[tk0 + i][d]);
        *(bf8v*)(vbT + ((size_t)h * 64 + d) * NTOK + tt * 64 + tk0) = v;
    }
}

// ---------------------------------------------------------------------------
// relW[h][n][kw] = sum_d q[h][n][d] * rel_pos_w[qw-kw+63][d]   (fp32)
// ---------------------------------------------------------------------------
__global__ __launch_bounds__(64) void relw_kernel(
    const float* __restrict__ q, const float* __restrict__ rpw,
    float* __restrict__ relW)
{
    __shared__ __align__(16) float qs[64];
    const int b = blockIdx.x, t = threadIdx.x;
    const int n = b & (NTOK - 1);
    const int qw = n & 63;
    qs[t] = q[(size_t)b * 64 + t];
    __syncthreads();
    const float* rw_ = rpw + (size_t)(qw - t + 63) * 64;
    float s = 0.f;
#pragma unroll
    for (int d = 0; d < 64; d += 4) {
        float4 q4 = *reinterpret_cast<const float4*>(&qs[d]);
        float4 w4 = *reinterpret_cast<const float4*>(rw_ + d);
        s += q4.x * w4.x + q4.y * w4.y + q4.z * w4.z + q4.w * w4.w;
    }
    relW[(size_t)b * 64 + t] = s;
}

// ---------------------------------------------------------------------------
// Flash attention, MFMA 16x16x32 bf16. Block = (head, 64-row q-tile), 4 waves.
// Wave w owns q-rows [16w,16w+16). relH computed in-kernel (qh==qt for the
// whole tile -> one MFMA tile-GEMM against reversed rph slice).
// ---------------------------------------------------------------------------
__global__ __launch_bounds__(256, 3) void flash_mfma_kernel(
    const float* __restrict__ qb, const short* __restrict__ kbh,
    const short* __restrict__ vbT, const float* __restrict__ rW,
    const float* __restrict__ rph, float* __restrict__ ao)
{
    __shared__ __align__(16) short Ks[64][72];   // [tok][d] bf16, pad 8
    __shared__ __align__(16) short Vt[64][72];   // [d][tok] bf16
    __shared__ __align__(16) short Ps[64][72];   // [qrow][tok] bf16
    __shared__ float relHs[64][64];              // [qrow][kt] fp32

    const int t = threadIdx.x;
    const int qt = blockIdx.x, head = blockIdx.y;
    const int row0 = qt * 64;
    const int lane = t & 63, w = t >> 6;
    const int l15 = lane & 15, l4 = lane >> 4;
    const size_t hB = (size_t)head * NTOK * 64;

    // Q A-fragments in registers: m=l15 (row 16w+l15), k = s*32 + l4*8 + j
    bf8v aQ[2];
    {
        const float* qsrc = qb + hB + (size_t)(row0 + 16 * w + l15) * 64;
#pragma unroll
        for (int s = 0; s < 2; ++s) {
            float4 u0 = *(const float4*)(qsrc + s * 32 + l4 * 8);
            float4 u1 = *(const float4*)(qsrc + s * 32 + l4 * 8 + 4);
            aQ[s] = pack8(u0, u1);
        }
    }
    // relW registers (fixed across k-tiles: kw == in-tile column)
    float rw[4][4];
#pragma unroll
    for (int nt = 0; nt < 4; ++nt)
#pragma unroll
        for (int r = 0; r < 4; ++r)
            rw[nt][r] = rW[hB + (size_t)(row0 + 16 * w + l4 * 4 + r) * 64 +
                           nt * 16 + l15];

    // relHs = Q @ rph[qt+63-kt]^T  (stage reversed slice into Ks, one GEMM)
    {
        const int rr = t >> 2, d0 = (t & 3) * 16;
        const float* src = rph + (size_t)(qt + 63 - rr) * 64 + d0;
        float4 a0 = *(const float4*)(src);
        float4 a1 = *(const float4*)(src + 4);
        float4 a2 = *(const float4*)(src + 8);
        float4 a3 = *(const float4*)(src + 12);
        *(bf8v*)&Ks[rr][d0] = pack8(a0, a1);
        *(bf8v*)&Ks[rr][d0 + 8] = pack8(a2, a3);
    }
    __syncthreads();
#pragma unroll
    for (int nt = 0; nt < 4; ++nt) {
        f4v c = {0.f, 0.f, 0.f, 0.f};
#pragma unroll
        for (int s = 0; s < 2; ++s) {
            bf8v b = *(const bf8v*)&Ks[nt * 16 + l15][s * 32 + l4 * 8];
            c = __builtin_amdgcn_mfma_f32_16x16x32_bf16(aQ[s], b, c, 0, 0, 0);
        }
#pragma unroll
        for (int r = 0; r < 4; ++r)
            relHs[16 * w + l4 * 4 + r][nt * 16 + l15] = c[r];
    }
    // (first loop-top __syncthreads makes relHs visible before first read)

    f4v O[4] = {{0.f, 0.f, 0.f, 0.f}, {0.f, 0.f, 0.f, 0.f},
                {0.f, 0.f, 0.f, 0.f}, {0.f, 0.f, 0.f, 0.f}};
    float m_run[4] = {-3e38f, -3e38f, -3e38f, -3e38f};
    float l_run[4] = {0.f, 0.f, 0.f, 0.f};

    for (int kt = 0; kt < 64; ++kt) {
        __syncthreads();   // previous consumers of Ks/Vt done
        {
            const int x = t >> 2, c0 = (t & 3) * 16;
            const short* ksrc = kbh + hB + (size_t)(kt * 64 + x) * 64 + c0;
            *(bf8v*)&Ks[x][c0] = *(const bf8v*)(ksrc);
            *(bf8v*)&Ks[x][c0 + 8] = *(const bf8v*)(ksrc + 8);
            const short* vsrc = vbT + ((size_t)head * 64 + x) * NTOK +
                                kt * 64 + c0;
            *(bf8v*)&Vt[x][c0] = *(const bf8v*)(vsrc);
            *(bf8v*)&Vt[x][c0 + 8] = *(const bf8v*)(vsrc + 8);
        }
        __syncthreads();

        // S = Q K^T (raw dot; scale+bias applied in fp32 epilogue)
        f4v acc[4] = {{0.f, 0.f, 0.f, 0.f}, {0.f, 0.f, 0.f, 0.f},
                      {0.f, 0.f, 0.f, 0.f}, {0.f, 0.f, 0.f, 0.f}};
#pragma unroll
        for (int s = 0; s < 2; ++s)
#pragma unroll
            for (int nt = 0; nt < 4; ++nt) {
                bf8v b = *(const bf8v*)&Ks[nt * 16 + l15][s * 32 + l4 * 8];
                acc[nt] = __builtin_amdgcn_mfma_f32_16x16x32_bf16(
                    aQ[s], b, acc[nt], 0, 0, 0);
            }

        float rh[4];
#pragma unroll
        for (int r = 0; r < 4; ++r)
            rh[r] = relHs[16 * w + l4 * 4 + r][kt];

        // scale + bias (fp32)
#pragma unroll
        for (int nt = 0; nt < 4; ++nt)
#pragma unroll
            for (int r = 0; r < 4; ++r)
                acc[nt][r] = fmaf(acc[nt][r], 0.125f, rh[r] + rw[nt][r]);

        // online softmax: rows live on 16 consecutive lanes -> DPP reduce
        float mt[4];
#pragma unroll
        for (int r = 0; r < 4; ++r)
            mt[r] = fmaxf(fmaxf(acc[0][r], acc[1][r]),
                          fmaxf(acc[2][r], acc[3][r]));
#pragma unroll
        for (int r = 0; r < 4; ++r) mt[r] = rowmax16(mt[r]);
        float alpha[4];
#pragma unroll
        for (int r = 0; r < 4; ++r) {
            const float mn = fmaxf(m_run[r], mt[r]);
            alpha[r] = __expf(m_run[r] - mn);
            m_run[r] = mn;
        }
        float srow[4] = {0.f, 0.f, 0.f, 0.f};
#pragma unroll
        for (int nt = 0; nt < 4; ++nt)
#pragma unroll
            for (int r = 0; r < 4; ++r) {
                const unsigned short pq = f2bf(__expf(acc[nt][r] - m_run[r]));
                srow[r] += bf2f(pq);   // l from quantized P: unbiased O/l
                Ps[16 * w + l4 * 4 + r][nt * 16 + l15] = (short)pq;
            }
#pragma unroll
        for (int r = 0; r < 4; ++r) srow[r] = rowsum16(srow[r]);
#pragma unroll
        for (int r = 0; r < 4; ++r)
            l_run[r] = l_run[r] * alpha[r] + srow[r];
#pragma unroll
        for (int nt = 0; nt < 4; ++nt)
#pragma unroll
            for (int r = 0; r < 4; ++r) O[nt][r] *= alpha[r];

        __syncthreads();   // P cross-lane visibility before A-frag reads

        // O += P V : A from Ps (m=l15), B from Vt (n=d)
#pragma unroll
        for (int s = 0; s < 2; ++s) {
            bf8v aP = *(const bf8v*)&Ps[16 * w + l15][s * 32 + l4 * 8];
#pragma unroll
            for (int nt = 0; nt < 4; ++nt) {
                bf8v b = *(const bf8v*)&Vt[nt * 16 + l15][s * 32 + l4 * 8];
                O[nt] = __builtin_amdgcn_mfma_f32_16x16x32_bf16(
                    aP, b, O[nt], 0, 0, 0);
            }
        }
    }

    // epilogue: normalize, store fp32 head-major
#pragma unroll
    for (int r = 0; r < 4; ++r) {
        const float inv = 1.0f / l_run[r];
        const size_t rowoff = hB + (size_t)(row0 + 16 * w + l4 * 4 + r) * 64;
#pragma unroll
        for (int nt = 0; nt < 4; ++nt)
            ao[rowoff + nt * 16 + l15] = O[nt][r] * inv;
    }
}

// ---------------------------------------------------------------------------
// Output projection: gathered head-major ao @ proj_w[768,768] + proj_b
// ---------------------------------------------------------------------------
__global__ __launch_bounds__(256) void proj_gemm_kernel(
    const float* __restrict__ ao, const float* __restrict__ w,
    const float* __restrict__ bias, float* __restrict__ out)
{
    __shared__ __align__(16) float As[16][64];
    __shared__ __align__(16) float Bs[16][64];
    const int t = threadIdx.x;
    const int row0 = blockIdx.y * 64;
    const int col0 = blockIdx.x * 64;
    const int tm = (t >> 4) << 2;
    const int tn = (t & 15) << 2;
    const int lm  = t >> 2;
    const int lk  = (t & 3) << 2;
    const int lbr = t >> 4;
    const int lbc = (t & 15) << 2;
    float acc[4][4] = {};
    for (int kk = 0; kk < 768; kk += 16) {
        const int c = kk + lk;
        const int h = c >> 6;
        const int d = c & 63;
        float4 av = *reinterpret_cast<const float4*>(
            ao + ((size_t)h * NTOK + row0 + lm) * 64 + d);
        float4 bv = *reinterpret_cast<const float4*>(
            w + (size_t)(kk + lbr) * 768 + col0 + lbc);
        As[lk + 0][lm] = av.x; As[lk + 1][lm] = av.y;
        As[lk + 2][lm] = av.z; As[lk + 3][lm] = av.w;
        *reinterpret_cast<float4*>(&Bs[lbr][lbc]) = bv;
        __syncthreads();
#pragma unroll
        for (int kq = 0; kq < 16; ++kq) {
            float4 a4 = *reinterpret_cast<const float4*>(&As[kq][tm]);
            float4 b4 = *reinterpret_cast<const float4*>(&Bs[kq][tn]);
            float a[4] = {a4.x, a4.y, a4.z, a4.w};
            float b[4] = {b4.x, b4.y, b4.z, b4.w};
#pragma unroll
            for (int ii = 0; ii < 4; ++ii)
#pragma unroll
                for (int jj = 0; jj < 4; ++jj)
                    acc[ii][jj] = fmaf(a[ii], b[jj], acc[ii][jj]);
        }
        __syncthreads();
    }
#pragma unroll
    for (int ii = 0; ii < 4; ++ii)
#pragma unroll
        for (int jj = 0; jj < 4; ++jj)
            out[(size_t)(row0 + tm + ii) * 768 + col0 + tn + jj] =
                acc[ii][jj] + bias[col0 + tn + jj];
}

// ---------------------------------------------------------------------------
extern "C" void kernel_launch(void* const* d_in, const int* in_sizes, int n_in,
                              void* d_out, int out_size, void* d_ws,
                              size_t ws_size, hipStream_t stream)
{
    (void)in_sizes; (void)n_in; (void)out_size; (void)ws_size;
    const float* x    = (const float*)d_in[0];
    const float* qkvw = (const float*)d_in[1];
    const float* qkvb = (const float*)d_in[2];
    const float* pw   = (const float*)d_in[3];
    const float* pb   = (const float*)d_in[4];
    const float* rph  = (const float*)d_in[5];
    const float* rpw  = (const float*)d_in[6];
    float* out = (float*)d_out;
    float* ws  = (float*)d_ws;

    const size_t S = (size_t)NHEADS * NTOK * 64;  // 3.1M elems per buffer
    float* qb = ws;                //  fp32 q (flash A-frags + relw)
    float* kb = ws + S;            //  fp32 k (prep input)
    float* vb = ws + 2 * S;        //  fp32 v (prep input)
    float* rW = ws + 3 * S;        //  fp32 relW table
    float* ao = ws + 4 * S;        //  fp32 attention output
    short* kbh = (short*)(ws + 5 * S);  // bf16 K  [h][tok][d]
    short* vbT = kbh + S;               // bf16 V^T [h][d][tok]
    // total: 5*S*4 + 2*S*2 = 75.5 MB (same footprint as round-1)

    qkv_gemm_kernel<<<dim3(36, 64), 256, 0, stream>>>(x, qkvw, qkvb, qb, kb, vb);
    prepk_kernel<<<dim3(64, NHEADS), 256, 0, stream>>>(kb, kbh);
    prepv_kernel<<<dim3(64, NHEADS), 256, 0, stream>>>(vb, vbT);
    relw_kernel<<<dim3(NHEADS * NTOK), 64, 0, stream>>>(qb, rpw, rW);
    flash_mfma_kernel<<<dim3(64, NHEADS), 256, 0, stream>>>(qb, kbh, vbT, rW,
                                                            rph, ao);
    proj_gemm_kernel<<<dim3(12, 64), 256, 0, stream>>>(ao, pw, pb, out);
}

// Round 3
// 375.941 us; speedup vs baseline: 3.6111x; 1.5627x over previous
//
#include <hip/hip_runtime.h>
#include <math.h>

// Problem constants: B=1, H=W=64 (N=4096), C=768, 12 heads x hd=64.
#define NHEADS 12
#define NTOK 4096

typedef __attribute__((ext_vector_type(8))) short bf8v;   // 8 x bf16 (4 VGPR)
typedef __attribute__((ext_vector_type(4))) float f4v;    // MFMA C/D frag

__device__ __forceinline__ unsigned short f2bf(float f) {
  unsigned int u = __float_as_uint(f);
  u += 0x7fffu + ((u >> 16) & 1u);   // RNE
  return (unsigned short)(u >> 16);
}
__device__ __forceinline__ float bf2f(unsigned short h) {
  return __uint_as_float(((unsigned int)h) << 16);
}
__device__ __forceinline__ bf8v pack8(float4 a, float4 b) {
  bf8v v;
  v[0] = (short)f2bf(a.x); v[1] = (short)f2bf(a.y);
  v[2] = (short)f2bf(a.z); v[3] = (short)f2bf(a.w);
  v[4] = (short)f2bf(b.x); v[5] = (short)f2bf(b.y);
  v[6] = (short)f2bf(b.z); v[7] = (short)f2bf(b.w);
  return v;
}
// async global->LDS, 16B per lane; lds dest must be wave-uniform base
__device__ __forceinline__ void gload_lds16(const void* g, void* l) {
  __builtin_amdgcn_global_load_lds(
      (const __attribute__((address_space(1))) void*)g,
      (__attribute__((address_space(3))) void*)l, 16, 0, 0);
}

// DPP rotate within 16-lane rows (C-layout rows are 16 consecutive lanes)
template <int CTRL>
__device__ __forceinline__ float dppmov(float x) {
  return __int_as_float(__builtin_amdgcn_update_dpp(
      0, __float_as_int(x), CTRL, 0xf, 0xf, true));
}
__device__ __forceinline__ float rowmax16(float x) {
  x = fmaxf(x, dppmov<0x128>(x));
  x = fmaxf(x, dppmov<0x124>(x));
  x = fmaxf(x, dppmov<0x122>(x));
  x = fmaxf(x, dppmov<0x121>(x));
  return x;
}
__device__ __forceinline__ float rowsum16(float x) {
  x += dppmov<0x128>(x);
  x += dppmov<0x124>(x);
  x += dppmov<0x122>(x);
  x += dppmov<0x121>(x);
  return x;
}

// ---------------------------------------------------------------------------
// cvt: fp32 -> bf16 elementwise (x), 8 elems/thread
// ---------------------------------------------------------------------------
__global__ __launch_bounds__(256) void cvt_kernel(
    const float* __restrict__ in, short* __restrict__ out)
{
    const size_t i = ((size_t)blockIdx.x * 256 + threadIdx.x) * 8;
    float4 a = *(const float4*)(in + i);
    float4 b = *(const float4*)(in + i + 4);
    *(bf8v*)(out + i) = pack8(a, b);
}

// ---------------------------------------------------------------------------
// tcvt: fp32 in[R][C] -> bf16 out[C][R] (64x64 LDS tiles)
// ---------------------------------------------------------------------------
__global__ __launch_bounds__(256) void tcvt_kernel(
    const float* __restrict__ in, short* __restrict__ out, int R, int C)
{
    __shared__ float Ts[64][65];
    const int bc = blockIdx.x * 64, br = blockIdx.y * 64, t = threadIdx.x;
    {
        const int r = t >> 2, c0 = (t & 3) * 16;
        const float* src = in + (size_t)(br + r) * C + bc + c0;
#pragma unroll
        for (int i = 0; i < 4; ++i) {
            float4 a = *(const float4*)(src + 4 * i);
            Ts[r][c0 + 4 * i + 0] = a.x;
            Ts[r][c0 + 4 * i + 1] = a.y;
            Ts[r][c0 + 4 * i + 2] = a.z;
            Ts[r][c0 + 4 * i + 3] = a.w;
        }
    }
    __syncthreads();
    const int c = t >> 2, r0 = (t & 3) * 16;
    short* dst = out + (size_t)(bc + c) * R + br + r0;
#pragma unroll
    for (int p = 0; p < 2; ++p) {
        bf8v v;
#pragma unroll
        for (int i = 0; i < 8; ++i) v[i] = (short)f2bf(Ts[r0 + p * 8 + i][c]);
        *(bf8v*)(dst + p * 8) = v;
    }
}

// ---------------------------------------------------------------------------
// QKV GEMM (MFMA bf16): C[m][n] = xh[m][k] @ wT[n][k]^T + bias[n]
// m97 structure: 128x128 tile, BK=32, global_load_lds 16B staging.
// Epilogue scatters to bf16 q/k [h][tok][d] and V^T [h][d][tok].
// ---------------------------------------------------------------------------
__global__ __launch_bounds__(256) void qkv_mfma_kernel(
    const short* __restrict__ xh, const short* __restrict__ wT,
    const float* __restrict__ bias, short* __restrict__ qbh,
    short* __restrict__ kbh, short* __restrict__ vbT)
{
    __shared__ __align__(16) short As[128 * 32];
    __shared__ __align__(16) short Bs[128 * 32];
    const int t = threadIdx.x;
    const int w = t >> 6, lane = t & 63;
    const int l15 = lane & 15, l4 = lane >> 4;
    const int wr = w >> 1, wc = w & 1;
    const int row0 = blockIdx.y * 128, col0 = blockIdx.x * 128;
    const int ldr = lane >> 2;        // row within 16-row chunk
    const int ldk = (lane & 3) * 8;   // k offset (shorts)

    f4v acc[4][4] = {};
    const short* aBase = xh + (size_t)(row0 + w * 32 + ldr) * 768 + ldk;
    const short* bBase = wT + (size_t)(col0 + w * 32 + ldr) * 768 + ldk;

    for (int kk = 0; kk < 768; kk += 32) {
        __syncthreads();
#pragma unroll
        for (int c = 0; c < 2; ++c) {
            gload_lds16(aBase + (size_t)c * 16 * 768 + kk,
                        &As[(w * 32 + c * 16) * 32]);
            gload_lds16(bBase + (size_t)c * 16 * 768 + kk,
                        &Bs[(w * 32 + c * 16) * 32]);
        }
        __syncthreads();
        bf8v af[4], bg[4];
#pragma unroll
        for (int i = 0; i < 4; ++i) {
            af[i] = *(const bf8v*)&As[(wr * 64 + 16 * i + l15) * 32 + l4 * 8];
            bg[i] = *(const bf8v*)&Bs[(wc * 64 + 16 * i + l15) * 32 + l4 * 8];
        }
#pragma unroll
        for (int i = 0; i < 4; ++i)
#pragma unroll
            for (int j = 0; j < 4; ++j)
                acc[i][j] = __builtin_amdgcn_mfma_f32_16x16x32_bf16(
                    af[i], bg[j], acc[i][j], 0, 0, 0);
    }

#pragma unroll
    for (int j = 0; j < 4; ++j) {
        const int n = col0 + wc * 64 + 16 * j + l15;
        const int s = n / 768;            // block-uniform (768 = 6*128)
        const int rm = n - s * 768;
        const int h = rm >> 6, d = rm & 63;
        const float bv = bias[n];
        if (s == 2) {
            short* vdst = vbT + (size_t)(h * 64 + d) * NTOK;
#pragma unroll
            for (int i = 0; i < 4; ++i) {
                const int m = row0 + wr * 64 + 16 * i + l4 * 4;
                short4 pv;
                pv.x = (short)f2bf(acc[i][j][0] + bv);
                pv.y = (short)f2bf(acc[i][j][1] + bv);
                pv.z = (short)f2bf(acc[i][j][2] + bv);
                pv.w = (short)f2bf(acc[i][j][3] + bv);
                *(short4*)(vdst + m) = pv;
            }
        } else {
            short* dst = (s == 0) ? qbh : kbh;
#pragma unroll
            for (int i = 0; i < 4; ++i) {
                const int m = row0 + wr * 64 + 16 * i + l4 * 4;
#pragma unroll
                for (int r = 0; r < 4; ++r)
                    dst[((size_t)h * NTOK + m + r) * 64 + d] =
                        (short)f2bf(acc[i][j][r] + bv);
            }
        }
    }
}

// ---------------------------------------------------------------------------
// relW[h][n][kw] = sum_d q[h][n][d] * rel_pos_w[qw-kw+63][d]   (fp32)
// ---------------------------------------------------------------------------
__global__ __launch_bounds__(64) void relw_kernel(
    const short* __restrict__ qbh, const float* __restrict__ rpw,
    float* __restrict__ relW)
{
    __shared__ __align__(16) float qs[64];
    const int b = blockIdx.x, t = threadIdx.x;
    const int n = b & (NTOK - 1);
    const int qw = n & 63;
    qs[t] = bf2f((unsigned short)qbh[(size_t)b * 64 + t]);
    __syncthreads();
    const float* rw_ = rpw + (size_t)(qw - t + 63) * 64;
    float s = 0.f;
#pragma unroll
    for (int d = 0; d < 64; d += 4) {
        float4 q4 = *reinterpret_cast<const float4*>(&qs[d]);
        float4 w4 = *reinterpret_cast<const float4*>(rw_ + d);
        s += q4.x * w4.x + q4.y * w4.y + q4.z * w4.z + q4.w * w4.w;
    }
    relW[(size_t)b * 64 + t] = s;
}

// ---------------------------------------------------------------------------
// Flash attention, MFMA 16x16x32 bf16. Block = (head, 64-row q-tile), 4 waves.
// ---------------------------------------------------------------------------
__global__ __launch_bounds__(256, 3) void flash_mfma_kernel(
    const short* __restrict__ qbh, const short* __restrict__ kbh,
    const short* __restrict__ vbT, const float* __restrict__ rW,
    const float* __restrict__ rph, short* __restrict__ aob)
{
    __shared__ __align__(16) short Ks[64][72];   // [tok][d] bf16, pad 8
    __shared__ __align__(16) short Vt[64][72];   // [d][tok] bf16
    __shared__ __align__(16) short Ps[64][72];   // [qrow][tok] bf16
    __shared__ float relHs[64][64];              // [qrow][kt] fp32

    const int t = threadIdx.x;
    const int qt = blockIdx.x, head = blockIdx.y;
    const int row0 = qt * 64;
    const int lane = t & 63, w = t >> 6;
    const int l15 = lane & 15, l4 = lane >> 4;
    const size_t hB = (size_t)head * NTOK * 64;

    // Q A-fragments direct bf16 load: m=l15 (row 16w+l15), k = s*32 + l4*8 + j
    bf8v aQ[2];
    {
        const short* qsrc = qbh + hB + (size_t)(row0 + 16 * w + l15) * 64;
#pragma unroll
        for (int s = 0; s < 2; ++s)
            aQ[s] = *(const bf8v*)(qsrc + s * 32 + l4 * 8);
    }
    // relW registers (fixed across k-tiles: kw == in-tile column)
    float rw[4][4];
#pragma unroll
    for (int nt = 0; nt < 4; ++nt)
#pragma unroll
        for (int r = 0; r < 4; ++r)
            rw[nt][r] = rW[hB + (size_t)(row0 + 16 * w + l4 * 4 + r) * 64 +
                           nt * 16 + l15];

    // relHs = Q @ rph[qt+63-kt]^T  (stage reversed slice into Ks, one GEMM)
    {
        const int rr = t >> 2, d0 = (t & 3) * 16;
        const float* src = rph + (size_t)(qt + 63 - rr) * 64 + d0;
        float4 a0 = *(const float4*)(src);
        float4 a1 = *(const float4*)(src + 4);
        float4 a2 = *(const float4*)(src + 8);
        float4 a3 = *(const float4*)(src + 12);
        *(bf8v*)&Ks[rr][d0] = pack8(a0, a1);
        *(bf8v*)&Ks[rr][d0 + 8] = pack8(a2, a3);
    }
    __syncthreads();
#pragma unroll
    for (int nt = 0; nt < 4; ++nt) {
        f4v c = {0.f, 0.f, 0.f, 0.f};
#pragma unroll
        for (int s = 0; s < 2; ++s) {
            bf8v b = *(const bf8v*)&Ks[nt * 16 + l15][s * 32 + l4 * 8];
            c = __builtin_amdgcn_mfma_f32_16x16x32_bf16(aQ[s], b, c, 0, 0, 0);
        }
#pragma unroll
        for (int r = 0; r < 4; ++r)
            relHs[16 * w + l4 * 4 + r][nt * 16 + l15] = c[r];
    }

    f4v O[4] = {{0.f, 0.f, 0.f, 0.f}, {0.f, 0.f, 0.f, 0.f},
                {0.f, 0.f, 0.f, 0.f}, {0.f, 0.f, 0.f, 0.f}};
    float m_run[4] = {-3e38f, -3e38f, -3e38f, -3e38f};
    float l_run[4] = {0.f, 0.f, 0.f, 0.f};

    for (int kt = 0; kt < 64; ++kt) {
        __syncthreads();
        {
            const int x = t >> 2, c0 = (t & 3) * 16;
            const short* ksrc = kbh + hB + (size_t)(kt * 64 + x) * 64 + c0;
            *(bf8v*)&Ks[x][c0] = *(const bf8v*)(ksrc);
            *(bf8v*)&Ks[x][c0 + 8] = *(const bf8v*)(ksrc + 8);
            const short* vsrc = vbT + ((size_t)head * 64 + x) * NTOK +
                                kt * 64 + c0;
            *(bf8v*)&Vt[x][c0] = *(const bf8v*)(vsrc);
            *(bf8v*)&Vt[x][c0 + 8] = *(const bf8v*)(vsrc + 8);
        }
        __syncthreads();

        f4v acc[4] = {{0.f, 0.f, 0.f, 0.f}, {0.f, 0.f, 0.f, 0.f},
                      {0.f, 0.f, 0.f, 0.f}, {0.f, 0.f, 0.f, 0.f}};
#pragma unroll
        for (int s = 0; s < 2; ++s)
#pragma unroll
            for (int nt = 0; nt < 4; ++nt) {
                bf8v b = *(const bf8v*)&Ks[nt * 16 + l15][s * 32 + l4 * 8];
                acc[nt] = __builtin_amdgcn_mfma_f32_16x16x32_bf16(
                    aQ[s], b, acc[nt], 0, 0, 0);
            }

        float rh[4];
#pragma unroll
        for (int r = 0; r < 4; ++r)
            rh[r] = relHs[16 * w + l4 * 4 + r][kt];

#pragma unroll
        for (int nt = 0; nt < 4; ++nt)
#pragma unroll
            for (int r = 0; r < 4; ++r)
                acc[nt][r] = fmaf(acc[nt][r], 0.125f, rh[r] + rw[nt][r]);

        float mt[4];
#pragma unroll
        for (int r = 0; r < 4; ++r)
            mt[r] = fmaxf(fmaxf(acc[0][r], acc[1][r]),
                          fmaxf(acc[2][r], acc[3][r]));
#pragma unroll
        for (int r = 0; r < 4; ++r) mt[r] = rowmax16(mt[r]);
        float alpha[4];
#pragma unroll
        for (int r = 0; r < 4; ++r) {
            const float mn = fmaxf(m_run[r], mt[r]);
            alpha[r] = __expf(m_run[r] - mn);
            m_run[r] = mn;
        }
        float srow[4] = {0.f, 0.f, 0.f, 0.f};
#pragma unroll
        for (int nt = 0; nt < 4; ++nt)
#pragma unroll
            for (int r = 0; r < 4; ++r) {
                const unsigned short pq = f2bf(__expf(acc[nt][r] - m_run[r]));
                srow[r] += bf2f(pq);
                Ps[16 * w + l4 * 4 + r][nt * 16 + l15] = (short)pq;
            }
#pragma unroll
        for (int r = 0; r < 4; ++r) srow[r] = rowsum16(srow[r]);
#pragma unroll
        for (int r = 0; r < 4; ++r)
            l_run[r] = l_run[r] * alpha[r] + srow[r];
#pragma unroll
        for (int nt = 0; nt < 4; ++nt)
#pragma unroll
            for (int r = 0; r < 4; ++r) O[nt][r] *= alpha[r];

        __syncthreads();

#pragma unroll
        for (int s = 0; s < 2; ++s) {
            bf8v aP = *(const bf8v*)&Ps[16 * w + l15][s * 32 + l4 * 8];
#pragma unroll
            for (int nt = 0; nt < 4; ++nt) {
                bf8v b = *(const bf8v*)&Vt[nt * 16 + l15][s * 32 + l4 * 8];
                O[nt] = __builtin_amdgcn_mfma_f32_16x16x32_bf16(
                    aP, b, O[nt], 0, 0, 0);
            }
        }
    }

    // epilogue: normalize, store bf16 in [tok][c] layout (proj's A operand)
#pragma unroll
    for (int r = 0; r < 4; ++r) {
        const float inv = 1.0f / l_run[r];
        const int row = row0 + 16 * w + l4 * 4 + r;
#pragma unroll
        for (int nt = 0; nt < 4; ++nt)
            aob[(size_t)row * 768 + head * 64 + nt * 16 + l15] =
                (short)f2bf(O[nt][r] * inv);
    }
}

// ---------------------------------------------------------------------------
// proj GEMM (MFMA bf16): out[m][n] = aob[m][k] @ pwT[n][k]^T + bias[n] (fp32)
// ---------------------------------------------------------------------------
__global__ __launch_bounds__(256) void proj_mfma_kernel(
    const short* __restrict__ aoh, const short* __restrict__ pwT,
    const float* __restrict__ bias, float* __restrict__ out)
{
    __shared__ __align__(16) short As[128 * 32];
    __shared__ __align__(16) short Bs[128 * 32];
    const int t = threadIdx.x;
    const int w = t >> 6, lane = t & 63;
    const int l15 = lane & 15, l4 = lane >> 4;
    const int wr = w >> 1, wc = w & 1;
    const int row0 = blockIdx.y * 128, col0 = blockIdx.x * 128;
    const int ldr = lane >> 2;
    const int ldk = (lane & 3) * 8;

    f4v acc[4][4] = {};
    const short* aBase = aoh + (size_t)(row0 + w * 32 + ldr) * 768 + ldk;
    const short* bBase = pwT + (size_t)(col0 + w * 32 + ldr) * 768 + ldk;

    for (int kk = 0; kk < 768; kk += 32) {
        __syncthreads();
#pragma unroll
        for (int c = 0; c < 2; ++c) {
            gload_lds16(aBase + (size_t)c * 16 * 768 + kk,
                        &As[(w * 32 + c * 16) * 32]);
            gload_lds16(bBase + (size_t)c * 16 * 768 + kk,
                        &Bs[(w * 32 + c * 16) * 32]);
        }
        __syncthreads();
        bf8v af[4], bg[4];
#pragma unroll
        for (int i = 0; i < 4; ++i) {
            af[i] = *(const bf8v*)&As[(wr * 64 + 16 * i + l15) * 32 + l4 * 8];
            bg[i] = *(const bf8v*)&Bs[(wc * 64 + 16 * i + l15) * 32 + l4 * 8];
        }
#pragma unroll
        for (int i = 0; i < 4; ++i)
#pragma unroll
            for (int j = 0; j < 4; ++j)
                acc[i][j] = __builtin_amdgcn_mfma_f32_16x16x32_bf16(
                    af[i], bg[j], acc[i][j], 0, 0, 0);
    }

#pragma unroll
    for (int j = 0; j < 4; ++j) {
        const int n = col0 + wc * 64 + 16 * j + l15;
        const float bv = bias[n];
#pragma unroll
        for (int i = 0; i < 4; ++i) {
            const int m = row0 + wr * 64 + 16 * i + l4 * 4;
#pragma unroll
            for (int r = 0; r < 4; ++r)
                out[(size_t)(m + r) * 768 + n] = acc[i][j][r] + bv;
        }
    }
}

// ---------------------------------------------------------------------------
extern "C" void kernel_launch(void* const* d_in, const int* in_sizes, int n_in,
                              void* d_out, int out_size, void* d_ws,
                              size_t ws_size, hipStream_t stream)
{
    (void)in_sizes; (void)n_in; (void)out_size; (void)ws_size;
    const float* x    = (const float*)d_in[0];
    const float* qkvw = (const float*)d_in[1];
    const float* qkvb = (const float*)d_in[2];
    const float* pw   = (const float*)d_in[3];
    const float* pb   = (const float*)d_in[4];
    const float* rph  = (const float*)d_in[5];
    const float* rpw  = (const float*)d_in[6];
    float* out = (float*)d_out;

    const size_t S = (size_t)NHEADS * NTOK * 64;  // 3,145,728 (= 4096*768)
    float* rW   = (float*)d_ws;          // S fp32   (12.6 MB)
    short* qbh  = (short*)(rW + S);      // S bf16   q  [h][tok][d]
    short* kbh  = qbh + S;               // S bf16   k  [h][tok][d]
    short* vbT  = kbh + S;               // S bf16   v^T [h][d][tok]
    short* xh   = vbT + S;               // S bf16   x  [tok][c]
    short* aob  = xh + S;                // S bf16   attn out [tok][c]
    short* wqkvT = aob + S;              // 2304*768 bf16
    short* pwT  = wqkvT + (size_t)2304 * 768;  // 768*768 bf16
    // total ~48.8 MB (< round-1/2's 75.5 MB footprint)

    cvt_kernel<<<dim3(1536), 256, 0, stream>>>(x, xh);
    tcvt_kernel<<<dim3(36, 12), 256, 0, stream>>>(qkvw, wqkvT, 768, 2304);
    tcvt_kernel<<<dim3(12, 12), 256, 0, stream>>>(pw, pwT, 768, 768);
    qkv_mfma_kernel<<<dim3(18, 32), 256, 0, stream>>>(xh, wqkvT, qkvb,
                                                      qbh, kbh, vbT);
    relw_kernel<<<dim3(NHEADS * NTOK), 64, 0, stream>>>(qbh, rpw, rW);
    flash_mfma_kernel<<<dim3(64, NHEADS), 256, 0, stream>>>(qbh, kbh, vbT, rW,
                                                            rph, aob);
    proj_mfma_kernel<<<dim3(6, 32), 256, 0, stream>>>(aob, pwT, pb, out);
}

// Round 4
// 283.901 us; speedup vs baseline: 4.7818x; 1.3242x over previous
//
#include <hip/hip_runtime.h>
#include <math.h>

// Problem constants: B=1, H=W=64 (N=4096), C=768, 12 heads x hd=64.
#define NHEADS 12
#define NTOK 4096
#define LOG2E 1.44269504f

typedef __attribute__((ext_vector_type(8))) short bf8v;   // 8 x bf16 (4 VGPR)
typedef __attribute__((ext_vector_type(4))) float f4v;    // MFMA C/D frag

__device__ __forceinline__ unsigned short f2bf(float f) {
  unsigned int u = __float_as_uint(f);
  u += 0x7fffu + ((u >> 16) & 1u);   // RNE
  return (unsigned short)(u >> 16);
}
__device__ __forceinline__ bf8v pack8(float4 a, float4 b) {
  bf8v v;
  v[0] = (short)f2bf(a.x); v[1] = (short)f2bf(a.y);
  v[2] = (short)f2bf(a.z); v[3] = (short)f2bf(a.w);
  v[4] = (short)f2bf(b.x); v[5] = (short)f2bf(b.y);
  v[6] = (short)f2bf(b.z); v[7] = (short)f2bf(b.w);
  return v;
}
// pack two f32 (already +0x8000 rounded) into (hi|lo) bf16 pair, 1 inst
__device__ __forceinline__ unsigned pkbf(float hi, float lo) {
  return __builtin_amdgcn_perm(__float_as_uint(hi) + 0x8000u,
                               __float_as_uint(lo) + 0x8000u, 0x07060302u);
}

// ---------------------------------------------------------------------------
// cvt: fp32 -> bf16 elementwise (x), 8 elems/thread
// ---------------------------------------------------------------------------
__global__ __launch_bounds__(256) void cvt_kernel(
    const float* __restrict__ in, short* __restrict__ out)
{
    const size_t i = ((size_t)blockIdx.x * 256 + threadIdx.x) * 8;
    float4 a = *(const float4*)(in + i);
    float4 b = *(const float4*)(in + i + 4);
    *(bf8v*)(out + i) = pack8(a, b);
}

// ---------------------------------------------------------------------------
// cvt_rpw: rel_pos_w fp32 [127][64] -> bf16 [128][64] (row 127 zeroed)
// ---------------------------------------------------------------------------
__global__ __launch_bounds__(256) void cvt_rpw_kernel(
    const float* __restrict__ in, short* __restrict__ out)
{
    const int idx = blockIdx.x * 256 + threadIdx.x;   // grid 32 -> 8192
    const float v = (idx < 127 * 64) ? in[idx] : 0.f;
    out[idx] = (short)f2bf(v);
}

// ---------------------------------------------------------------------------
// tcvt: fp32 in[R][C] -> bf16 out[C][R] (64x64 LDS tiles)
// ---------------------------------------------------------------------------
__global__ __launch_bounds__(256) void tcvt_kernel(
    const float* __restrict__ in, short* __restrict__ out, int R, int C)
{
    __shared__ float Ts[64][65];
    const int bc = blockIdx.x * 64, br = blockIdx.y * 64, t = threadIdx.x;
    {
        const int r = t >> 2, c0 = (t & 3) * 16;
        const float* src = in + (size_t)(br + r) * C + bc + c0;
#pragma unroll
        for (int i = 0; i < 4; ++i) {
            float4 a = *(const float4*)(src + 4 * i);
            Ts[r][c0 + 4 * i + 0] = a.x;
            Ts[r][c0 + 4 * i + 1] = a.y;
            Ts[r][c0 + 4 * i + 2] = a.z;
            Ts[r][c0 + 4 * i + 3] = a.w;
        }
    }
    __syncthreads();
    const int c = t >> 2, r0 = (t & 3) * 16;
    short* dst = out + (size_t)(bc + c) * R + br + r0;
#pragma unroll
    for (int p = 0; p < 2; ++p) {
        bf8v v;
#pragma unroll
        for (int i = 0; i < 8; ++i) v[i] = (short)f2bf(Ts[r0 + p * 8 + i][c]);
        *(bf8v*)(dst + p * 8) = v;
    }
}

// ---------------------------------------------------------------------------
// QKV GEMM (MFMA bf16): C[m][n] = xh[m][k] @ wT[n][k]^T + bias[n]
// ---------------------------------------------------------------------------
__device__ __forceinline__ void gload_lds16(const void* g, void* l) {
  __builtin_amdgcn_global_load_lds(
      (const __attribute__((address_space(1))) void*)g,
      (__attribute__((address_space(3))) void*)l, 16, 0, 0);
}

__global__ __launch_bounds__(256) void qkv_mfma_kernel(
    const short* __restrict__ xh, const short* __restrict__ wT,
    const float* __restrict__ bias, short* __restrict__ qbh,
    short* __restrict__ kbh, short* __restrict__ vbT)
{
    __shared__ __align__(16) short As[128 * 32];
    __shared__ __align__(16) short Bs[128 * 32];
    const int t = threadIdx.x;
    const int w = t >> 6, lane = t & 63;
    const int l15 = lane & 15, l4 = lane >> 4;
    const int wr = w >> 1, wc = w & 1;
    const int row0 = blockIdx.y * 128, col0 = blockIdx.x * 128;
    const int ldr = lane >> 2;
    const int ldk = (lane & 3) * 8;

    f4v acc[4][4] = {};
    const short* aBase = xh + (size_t)(row0 + w * 32 + ldr) * 768 + ldk;
    const short* bBase = wT + (size_t)(col0 + w * 32 + ldr) * 768 + ldk;

    for (int kk = 0; kk < 768; kk += 32) {
        __syncthreads();
#pragma unroll
        for (int c = 0; c < 2; ++c) {
            gload_lds16(aBase + (size_t)c * 16 * 768 + kk,
                        &As[(w * 32 + c * 16) * 32]);
            gload_lds16(bBase + (size_t)c * 16 * 768 + kk,
                        &Bs[(w * 32 + c * 16) * 32]);
        }
        __syncthreads();
        bf8v af[4], bg[4];
#pragma unroll
        for (int i = 0; i < 4; ++i) {
            af[i] = *(const bf8v*)&As[(wr * 64 + 16 * i + l15) * 32 + l4 * 8];
            bg[i] = *(const bf8v*)&Bs[(wc * 64 + 16 * i + l15) * 32 + l4 * 8];
        }
#pragma unroll
        for (int i = 0; i < 4; ++i)
#pragma unroll
            for (int j = 0; j < 4; ++j)
                acc[i][j] = __builtin_amdgcn_mfma_f32_16x16x32_bf16(
                    af[i], bg[j], acc[i][j], 0, 0, 0);
    }

#pragma unroll
    for (int j = 0; j < 4; ++j) {
        const int n = col0 + wc * 64 + 16 * j + l15;
        const int s = n / 768;            // block-uniform (768 = 6*128)
        const int rm = n - s * 768;
        const int h = rm >> 6, d = rm & 63;
        const float bv = bias[n];
        if (s == 2) {
            short* vdst = vbT + (size_t)(h * 64 + d) * NTOK;
#pragma unroll
            for (int i = 0; i < 4; ++i) {
                const int m = row0 + wr * 64 + 16 * i + l4 * 4;
                short4 pv;
                pv.x = (short)f2bf(acc[i][j][0] + bv);
                pv.y = (short)f2bf(acc[i][j][1] + bv);
                pv.z = (short)f2bf(acc[i][j][2] + bv);
                pv.w = (short)f2bf(acc[i][j][3] + bv);
                *(short4*)(vdst + m) = pv;
            }
        } else {
            short* dst = (s == 0) ? qbh : kbh;
#pragma unroll
            for (int i = 0; i < 4; ++i) {
                const int m = row0 + wr * 64 + 16 * i + l4 * 4;
#pragma unroll
                for (int r = 0; r < 4; ++r)
                    dst[((size_t)h * NTOK + m + r) * 64 + d] =
                        (short)f2bf(acc[i][j][r] + bv);
            }
        }
    }
}

// ---------------------------------------------------------------------------
// relu: U[j][qw] = sum_d rpwb[j][d] * Q[h][qh*64+qw][d]  (MFMA, per (h,qh))
// then relW[h][qh*64+qw][kw] = LOG2E * U[qw+63-kw][qw]   (LDS gather)
// ---------------------------------------------------------------------------
__global__ __launch_bounds__(256) void relu_kernel(
    const short* __restrict__ qbh, const short* __restrict__ rpwb,
    float* __restrict__ rW)
{
    __shared__ float Us[128][65];
    const int h = blockIdx.x, qh = blockIdx.y;
    const int t = threadIdx.x, w = t >> 6, lane = t & 63;
    const int l15 = lane & 15, l4 = lane >> 4;
    const size_t hB = (size_t)h * NTOK * 64;

    bf8v bq[4][2];
#pragma unroll
    for (int nt = 0; nt < 4; ++nt) {
        const short* qs = qbh + hB + (size_t)(qh * 64 + nt * 16 + l15) * 64;
#pragma unroll
        for (int s = 0; s < 2; ++s)
            bq[nt][s] = *(const bf8v*)(qs + s * 32 + l4 * 8);
    }
    bf8v aw[2][2];
#pragma unroll
    for (int mi = 0; mi < 2; ++mi) {
        const short* as = rpwb + (size_t)((w * 2 + mi) * 16 + l15) * 64;
#pragma unroll
        for (int s = 0; s < 2; ++s)
            aw[mi][s] = *(const bf8v*)(as + s * 32 + l4 * 8);
    }
    f4v U[2][4] = {};
#pragma unroll
    for (int mi = 0; mi < 2; ++mi)
#pragma unroll
        for (int nt = 0; nt < 4; ++nt)
#pragma unroll
            for (int s = 0; s < 2; ++s)
                U[mi][nt] = __builtin_amdgcn_mfma_f32_16x16x32_bf16(
                    aw[mi][s], bq[nt][s], U[mi][nt], 0, 0, 0);
#pragma unroll
    for (int mi = 0; mi < 2; ++mi)
#pragma unroll
        for (int nt = 0; nt < 4; ++nt)
#pragma unroll
            for (int r = 0; r < 4; ++r)
                Us[(w * 2 + mi) * 16 + l4 * 4 + r][nt * 16 + l15] =
                    U[mi][nt][r];
    __syncthreads();
    const int kw = t & 63, q0 = t >> 6;
#pragma unroll
    for (int i = 0; i < 16; ++i) {
        const int q = q0 * 16 + i;
        rW[hB + (size_t)(qh * 64 + q) * 64 + kw] =
            Us[q + 63 - kw][q] * LOG2E;
    }
}

// ---------------------------------------------------------------------------
// Flash attention, S^T formulation. Block = (q-tile 64, head), 4 waves.
// S^T = K·Q^T so each lane owns ONE softmax row (q = 16w + lane&15).
// P C->A layout transform done in-register (v_perm pack + ds_bpermute).
// ---------------------------------------------------------------------------
__global__ __launch_bounds__(256, 3) void flash_mfma_kernel(
    const short* __restrict__ qbh, const short* __restrict__ kbh,
    const short* __restrict__ vbT, const float* __restrict__ rW,
    const float* __restrict__ rph, short* __restrict__ aob)
{
    __shared__ __align__(16) short Ks[64][72];   // [tok][d] bf16, pad 8
    __shared__ __align__(16) short Vt[64][72];   // [d][tok] bf16
    __shared__ float relHs[64][65];              // [kt][q-local] fp32 (log2e)

    const int t = threadIdx.x;
    const int qt = blockIdx.x, head = blockIdx.y;
    const int row0 = qt * 64;
    const int lane = t & 63, w = t >> 6;
    const int l15 = lane & 15, l4 = lane >> 4;
    const size_t hB = (size_t)head * NTOK * 64;
    const float SC = 0.125f * LOG2E;

    // Q as B-fragments (n = q-row = 16w + l15), k = s*32 + l4*8 + j
    bf8v bQ[2];
    {
        const short* qsrc = qbh + hB + (size_t)(row0 + 16 * w + l15) * 64;
#pragma unroll
        for (int s = 0; s < 2; ++s)
            bQ[s] = *(const bf8v*)(qsrc + s * 32 + l4 * 8);
    }
    // relW preload (already LOG2E-scaled): element (q=l15row, kw=16nt+4l4+r)
    float rw[4][4];
#pragma unroll
    for (int nt = 0; nt < 4; ++nt)
#pragma unroll
        for (int r = 0; r < 4; ++r)
            rw[nt][r] = rW[hB + (size_t)(row0 + 16 * w + l15) * 64 +
                           nt * 16 + l4 * 4 + r];

    // stage reversed rph slice (x LOG2E) into Ks for the relH GEMM
    {
        const int rr = t >> 2, d0 = (t & 3) * 16;
        const float* src = rph + (size_t)(qt + 63 - rr) * 64 + d0;
        float4 a0 = *(const float4*)(src);
        float4 a1 = *(const float4*)(src + 4);
        float4 a2 = *(const float4*)(src + 8);
        float4 a3 = *(const float4*)(src + 12);
        a0.x *= LOG2E; a0.y *= LOG2E; a0.z *= LOG2E; a0.w *= LOG2E;
        a1.x *= LOG2E; a1.y *= LOG2E; a1.z *= LOG2E; a1.w *= LOG2E;
        a2.x *= LOG2E; a2.y *= LOG2E; a2.z *= LOG2E; a2.w *= LOG2E;
        a3.x *= LOG2E; a3.y *= LOG2E; a3.z *= LOG2E; a3.w *= LOG2E;
        *(bf8v*)&Ks[rr][d0] = pack8(a0, a1);
        *(bf8v*)&Ks[rr][d0 + 8] = pack8(a2, a3);
    }
    // prefetch K/V tile 0 into registers
    const int sx = t >> 2, sc = (t & 3) * 16;
    const short* kptr = kbh + hB + (size_t)sx * 64 + sc;
    const short* vptr = vbT + ((size_t)head * 64 + sx) * NTOK + sc;
    bf8v kpf0 = *(const bf8v*)(kptr), kpf1 = *(const bf8v*)(kptr + 8);
    bf8v vpf0 = *(const bf8v*)(vptr), vpf1 = *(const bf8v*)(vptr + 8);

    __syncthreads();
    // relHs = rph_rev · Q^T  (m = kt, n = q-local)
#pragma unroll
    for (int nt = 0; nt < 4; ++nt) {
        f4v c = {0.f, 0.f, 0.f, 0.f};
#pragma unroll
        for (int s = 0; s < 2; ++s)
            c = __builtin_amdgcn_mfma_f32_16x16x32_bf16(
                *(const bf8v*)&Ks[nt * 16 + l15][s * 32 + l4 * 8], bQ[s], c,
                0, 0, 0);
#pragma unroll
        for (int r = 0; r < 4; ++r)
            relHs[nt * 16 + l4 * 4 + r][16 * w + l15] = c[r];
    }

    f4v O[4] = {{0.f, 0.f, 0.f, 0.f}, {0.f, 0.f, 0.f, 0.f},
                {0.f, 0.f, 0.f, 0.f}, {0.f, 0.f, 0.f, 0.f}};
    float m_run = -3.0e38f, l_run = 0.f;

    const int abase = (lane >> 2) & 12;                 // 4*l4
    const int xsel = ((lane >> 4) & 1) * 32 + l15;      // transform src lane
    const bool lo32 = (lane < 32);

    for (int kt = 0; kt < 64; ++kt) {
        __syncthreads();
        *(bf8v*)&Ks[sx][sc] = kpf0; *(bf8v*)&Ks[sx][sc + 8] = kpf1;
        *(bf8v*)&Vt[sx][sc] = vpf0; *(bf8v*)&Vt[sx][sc + 8] = vpf1;
        {
            const int ktn = (kt < 63) ? kt + 1 : 63;
            const short* kp = kptr + (size_t)ktn * 4096;
            const short* vp = vptr + ktn * 64;
            kpf0 = *(const bf8v*)kp; kpf1 = *(const bf8v*)(kp + 8);
            vpf0 = *(const bf8v*)vp; vpf1 = *(const bf8v*)(vp + 8);
        }
        __syncthreads();

        // S^T tile: acc[nt] rows = tokens 16nt+4*l4+r, col = q = l15
        f4v acc[4] = {{0.f, 0.f, 0.f, 0.f}, {0.f, 0.f, 0.f, 0.f},
                      {0.f, 0.f, 0.f, 0.f}, {0.f, 0.f, 0.f, 0.f}};
#pragma unroll
        for (int s = 0; s < 2; ++s)
#pragma unroll
            for (int nt = 0; nt < 4; ++nt)
                acc[nt] = __builtin_amdgcn_mfma_f32_16x16x32_bf16(
                    *(const bf8v*)&Ks[nt * 16 + l15][s * 32 + l4 * 8], bQ[s],
                    acc[nt], 0, 0, 0);

        const float rh = relHs[kt][16 * w + l15];   // broadcast read

        // v = SC*acc + rw  (rh folded into the max/exp shift)
        float v[4][4];
#pragma unroll
        for (int nt = 0; nt < 4; ++nt)
#pragma unroll
            for (int r = 0; r < 4; ++r)
                v[nt][r] = fmaf(acc[nt][r], SC, rw[nt][r]);

        float mt;
        {
            float m0 = fmaxf(fmaxf(v[0][0], v[0][1]), fmaxf(v[0][2], v[0][3]));
            float m1 = fmaxf(fmaxf(v[1][0], v[1][1]), fmaxf(v[1][2], v[1][3]));
            float m2 = fmaxf(fmaxf(v[2][0], v[2][1]), fmaxf(v[2][2], v[2][3]));
            float m3 = fmaxf(fmaxf(v[3][0], v[3][1]), fmaxf(v[3][2], v[3][3]));
            mt = fmaxf(fmaxf(m0, m1), fmaxf(m2, m3));
        }
        mt = fmaxf(mt, __shfl_xor(mt, 16));
        mt = fmaxf(mt, __shfl_xor(mt, 32));
        mt += rh;
        const float mnew = fmaxf(m_run, mt);
        const float alpha = __builtin_amdgcn_exp2f(m_run - mnew);
        m_run = mnew;
        const float mb = mnew - rh;

        float e[4][4];
#pragma unroll
        for (int nt = 0; nt < 4; ++nt)
#pragma unroll
            for (int r = 0; r < 4; ++r)
                e[nt][r] = __builtin_amdgcn_exp2f(v[nt][r] - mb);
        float srow;
        {
            float s0 = (e[0][0] + e[0][1]) + (e[0][2] + e[0][3]);
            float s1 = (e[1][0] + e[1][1]) + (e[1][2] + e[1][3]);
            float s2 = (e[2][0] + e[2][1]) + (e[2][2] + e[2][3]);
            float s3 = (e[3][0] + e[3][1]) + (e[3][2] + e[3][3]);
            srow = (s0 + s1) + (s2 + s3);
        }
        srow += __shfl_xor(srow, 16);
        srow += __shfl_xor(srow, 32);
        l_run = l_run * alpha + srow;

        // pack P to bf16 pairs (r0|r1), (r2|r3) per tile
        unsigned pk[4][2];
#pragma unroll
        for (int nt = 0; nt < 4; ++nt) {
            pk[nt][0] = pkbf(e[nt][1], e[nt][0]);
            pk[nt][1] = pkbf(e[nt][3], e[nt][2]);
        }
        // C->A quad permutation: A_j quads = [x.q0,x.q2,y.q0,y.q2] (j<4),
        //                        A_{j+4}   = [x.q1,x.q3,y.q1,y.q3]
        bf8v aP[2];
#pragma unroll
        for (int s = 0; s < 2; ++s) {
            const int x0 = __shfl((int)pk[2 * s][0], xsel);
            const int y0 = __shfl((int)pk[2 * s + 1][0], xsel);
            const int x1 = __shfl((int)pk[2 * s][1], xsel);
            const int y1 = __shfl((int)pk[2 * s + 1][1], xsel);
            const int x2 = __shfl((int)pk[2 * s][0], xsel + 16);
            const int y2 = __shfl((int)pk[2 * s + 1][0], xsel + 16);
            const int x3 = __shfl((int)pk[2 * s][1], xsel + 16);
            const int y3 = __shfl((int)pk[2 * s + 1][1], xsel + 16);
            int4 av;
            av.x = lo32 ? x0 : y0;
            av.y = lo32 ? x1 : y1;
            av.z = lo32 ? x2 : y2;
            av.w = lo32 ? x3 : y3;
            union { int4 i; bf8v v; } u; u.i = av;
            aP[s] = u.v;
        }
        // O rescale (alpha indexed by O-row = l4*4+r)
        float ar[4];
#pragma unroll
        for (int r = 0; r < 4; ++r) ar[r] = __shfl(alpha, abase + r);
#pragma unroll
        for (int nt = 0; nt < 4; ++nt)
#pragma unroll
            for (int r = 0; r < 4; ++r) O[nt][r] *= ar[r];
        // O += P V
#pragma unroll
        for (int s = 0; s < 2; ++s)
#pragma unroll
            for (int nt = 0; nt < 4; ++nt)
                O[nt] = __builtin_amdgcn_mfma_f32_16x16x32_bf16(
                    aP[s], *(const bf8v*)&Vt[nt * 16 + l15][s * 32 + l4 * 8],
                    O[nt], 0, 0, 0);
    }

    // epilogue: normalize (l indexed by O-row), store bf16 [tok][c]
    const float linv = 1.0f / l_run;
    float li[4];
#pragma unroll
    for (int r = 0; r < 4; ++r) li[r] = __shfl(linv, abase + r);
#pragma unroll
    for (int r = 0; r < 4; ++r) {
        const int row = row0 + 16 * w + l4 * 4 + r;
#pragma unroll
        for (int nt = 0; nt < 4; ++nt)
            aob[(size_t)row * 768 + head * 64 + nt * 16 + l15] =
                (short)f2bf(O[nt][r] * li[r]);
    }
}

// ---------------------------------------------------------------------------
// proj GEMM (MFMA bf16): out[m][n] = aob[m][k] @ pwT[n][k]^T + bias[n] (fp32)
// ---------------------------------------------------------------------------
__global__ __launch_bounds__(256) void proj_mfma_kernel(
    const short* __restrict__ aoh, const short* __restrict__ pwT,
    const float* __restrict__ bias, float* __restrict__ out)
{
    __shared__ __align__(16) short As[128 * 32];
    __shared__ __align__(16) short Bs[128 * 32];
    const int t = threadIdx.x;
    const int w = t >> 6, lane = t & 63;
    const int l15 = lane & 15, l4 = lane >> 4;
    const int wr = w >> 1, wc = w & 1;
    const int row0 = blockIdx.y * 128, col0 = blockIdx.x * 128;
    const int ldr = lane >> 2;
    const int ldk = (lane & 3) * 8;

    f4v acc[4][4] = {};
    const short* aBase = aoh + (size_t)(row0 + w * 32 + ldr) * 768 + ldk;
    const short* bBase = pwT + (size_t)(col0 + w * 32 + ldr) * 768 + ldk;

    for (int kk = 0; kk < 768; kk += 32) {
        __syncthreads();
#pragma unroll
        for (int c = 0; c < 2; ++c) {
            gload_lds16(aBase + (size_t)c * 16 * 768 + kk,
                        &As[(w * 32 + c * 16) * 32]);
            gload_lds16(bBase + (size_t)c * 16 * 768 + kk,
                        &Bs[(w * 32 + c * 16) * 32]);
        }
        __syncthreads();
        bf8v af[4], bg[4];
#pragma unroll
        for (int i = 0; i < 4; ++i) {
            af[i] = *(const bf8v*)&As[(wr * 64 + 16 * i + l15) * 32 + l4 * 8];
            bg[i] = *(const bf8v*)&Bs[(wc * 64 + 16 * i + l15) * 32 + l4 * 8];
        }
#pragma unroll
        for (int i = 0; i < 4; ++i)
#pragma unroll
            for (int j = 0; j < 4; ++j)
                acc[i][j] = __builtin_amdgcn_mfma_f32_16x16x32_bf16(
                    af[i], bg[j], acc[i][j], 0, 0, 0);
    }

#pragma unroll
    for (int j = 0; j < 4; ++j) {
        const int n = col0 + wc * 64 + 16 * j + l15;
        const float bv = bias[n];
#pragma unroll
        for (int i = 0; i < 4; ++i) {
            const int m = row0 + wr * 64 + 16 * i + l4 * 4;
#pragma unroll
            for (int r = 0; r < 4; ++r)
                out[(size_t)(m + r) * 768 + n] = acc[i][j][r] + bv;
        }
    }
}

// ---------------------------------------------------------------------------
extern "C" void kernel_launch(void* const* d_in, const int* in_sizes, int n_in,
                              void* d_out, int out_size, void* d_ws,
                              size_t ws_size, hipStream_t stream)
{
    (void)in_sizes; (void)n_in; (void)out_size; (void)ws_size;
    const float* x    = (const float*)d_in[0];
    const float* qkvw = (const float*)d_in[1];
    const float* qkvb = (const float*)d_in[2];
    const float* pw   = (const float*)d_in[3];
    const float* pb   = (const float*)d_in[4];
    const float* rph  = (const float*)d_in[5];
    const float* rpw  = (const float*)d_in[6];
    float* out = (float*)d_out;

    const size_t S = (size_t)NHEADS * NTOK * 64;  // 3,145,728 (= 4096*768)
    float* rW   = (float*)d_ws;          // S fp32 relW (LOG2E-scaled)
    short* qbh  = (short*)(rW + S);      // S bf16   q  [h][tok][d]
    short* kbh  = qbh + S;               // S bf16   k  [h][tok][d]
    short* vbT  = kbh + S;               // S bf16   v^T [h][d][tok]
    short* xh   = vbT + S;               // S bf16   x  [tok][c]
    short* aob  = xh + S;                // S bf16   attn out [tok][c]
    short* wqkvT = aob + S;              // 2304*768 bf16
    short* pwT  = wqkvT + (size_t)2304 * 768;  // 768*768 bf16
    short* rpwb = pwT + (size_t)768 * 768;     // 128*64 bf16 rel_pos_w
    // total ~48.8 MB

    cvt_kernel<<<dim3(1536), 256, 0, stream>>>(x, xh);
    tcvt_kernel<<<dim3(36, 12), 256, 0, stream>>>(qkvw, wqkvT, 768, 2304);
    tcvt_kernel<<<dim3(12, 12), 256, 0, stream>>>(pw, pwT, 768, 768);
    cvt_rpw_kernel<<<dim3(32), 256, 0, stream>>>(rpw, rpwb);
    qkv_mfma_kernel<<<dim3(18, 32), 256, 0, stream>>>(xh, wqkvT, qkvb,
                                                      qbh, kbh, vbT);
    relu_kernel<<<dim3(NHEADS, 64), 256, 0, stream>>>(qbh, rpwb, rW);
    flash_mfma_kernel<<<dim3(64, NHEADS), 256, 0, stream>>>(qbh, kbh, vbT, rW,
                                                            rph, aob);
    proj_mfma_kernel<<<dim3(6, 32), 256, 0, stream>>>(aob, pwT, pb, out);
}

// Round 5
// 273.718 us; speedup vs baseline: 4.9597x; 1.0372x over previous
//
#include <hip/hip_runtime.h>
#include <math.h>

// Problem constants: B=1, H=W=64 (N=4096), C=768, 12 heads x hd=64.
#define NHEADS 12
#define NTOK 4096
#define LOG2E 1.44269504f

typedef __attribute__((ext_vector_type(8))) short bf8v;   // 8 x bf16 (4 VGPR)
typedef __attribute__((ext_vector_type(4))) float f4v;    // MFMA C/D frag

__device__ __forceinline__ unsigned short f2bf(float f) {
  unsigned int u = __float_as_uint(f);
  u += 0x7fffu + ((u >> 16) & 1u);   // RNE
  return (unsigned short)(u >> 16);
}
__device__ __forceinline__ bf8v pack8(float4 a, float4 b) {
  bf8v v;
  v[0] = (short)f2bf(a.x); v[1] = (short)f2bf(a.y);
  v[2] = (short)f2bf(a.z); v[3] = (short)f2bf(a.w);
  v[4] = (short)f2bf(b.x); v[5] = (short)f2bf(b.y);
  v[6] = (short)f2bf(b.z); v[7] = (short)f2bf(b.w);
  return v;
}
// pack two f32 (round-to-nearest-ish via +0x8000) into (hi|lo) bf16 pair
__device__ __forceinline__ unsigned pkbf(float hi, float lo) {
  return __builtin_amdgcn_perm(__float_as_uint(hi) + 0x8000u,
                               __float_as_uint(lo) + 0x8000u, 0x07060302u);
}

// ---------------------------------------------------------------------------
// cvt: fp32 -> bf16 elementwise (x), 8 elems/thread
// ---------------------------------------------------------------------------
__global__ __launch_bounds__(256) void cvt_kernel(
    const float* __restrict__ in, short* __restrict__ out)
{
    const size_t i = ((size_t)blockIdx.x * 256 + threadIdx.x) * 8;
    float4 a = *(const float4*)(in + i);
    float4 b = *(const float4*)(in + i + 4);
    *(bf8v*)(out + i) = pack8(a, b);
}

// ---------------------------------------------------------------------------
// cvt_rpw: rel_pos_w fp32 [127][64] -> bf16 [128][64] (row 127 zeroed)
// ---------------------------------------------------------------------------
__global__ __launch_bounds__(256) void cvt_rpw_kernel(
    const float* __restrict__ in, short* __restrict__ out)
{
    const int idx = blockIdx.x * 256 + threadIdx.x;   // grid 32 -> 8192
    const float v = (idx < 127 * 64) ? in[idx] : 0.f;
    out[idx] = (short)f2bf(v);
}

// ---------------------------------------------------------------------------
// tcvt: fp32 in[R][C] -> bf16 out[C][R] (64x64 LDS tiles)
// ---------------------------------------------------------------------------
__global__ __launch_bounds__(256) void tcvt_kernel(
    const float* __restrict__ in, short* __restrict__ out, int R, int C)
{
    __shared__ float Ts[64][65];
    const int bc = blockIdx.x * 64, br = blockIdx.y * 64, t = threadIdx.x;
    {
        const int r = t >> 2, c0 = (t & 3) * 16;
        const float* src = in + (size_t)(br + r) * C + bc + c0;
#pragma unroll
        for (int i = 0; i < 4; ++i) {
            float4 a = *(const float4*)(src + 4 * i);
            Ts[r][c0 + 4 * i + 0] = a.x;
            Ts[r][c0 + 4 * i + 1] = a.y;
            Ts[r][c0 + 4 * i + 2] = a.z;
            Ts[r][c0 + 4 * i + 3] = a.w;
        }
    }
    __syncthreads();
    const int c = t >> 2, r0 = (t & 3) * 16;
    short* dst = out + (size_t)(bc + c) * R + br + r0;
#pragma unroll
    for (int p = 0; p < 2; ++p) {
        bf8v v;
#pragma unroll
        for (int i = 0; i < 8; ++i) v[i] = (short)f2bf(Ts[r0 + p * 8 + i][c]);
        *(bf8v*)(dst + p * 8) = v;
    }
}

// ---------------------------------------------------------------------------
// QKV GEMM (MFMA bf16): C[m][n] = xh[m][k] @ wT[n][k]^T + bias[n]
// ---------------------------------------------------------------------------
__device__ __forceinline__ void gload_lds16(const void* g, void* l) {
  __builtin_amdgcn_global_load_lds(
      (const __attribute__((address_space(1))) void*)g,
      (__attribute__((address_space(3))) void*)l, 16, 0, 0);
}

__global__ __launch_bounds__(256) void qkv_mfma_kernel(
    const short* __restrict__ xh, const short* __restrict__ wT,
    const float* __restrict__ bias, short* __restrict__ qbh,
    short* __restrict__ kbh, short* __restrict__ vbT)
{
    __shared__ __align__(16) short As[128 * 32];
    __shared__ __align__(16) short Bs[128 * 32];
    const int t = threadIdx.x;
    const int w = t >> 6, lane = t & 63;
    const int l15 = lane & 15, l4 = lane >> 4;
    const int wr = w >> 1, wc = w & 1;
    const int row0 = blockIdx.y * 128, col0 = blockIdx.x * 128;
    const int ldr = lane >> 2;
    const int ldk = (lane & 3) * 8;

    f4v acc[4][4] = {};
    const short* aBase = xh + (size_t)(row0 + w * 32 + ldr) * 768 + ldk;
    const short* bBase = wT + (size_t)(col0 + w * 32 + ldr) * 768 + ldk;

    for (int kk = 0; kk < 768; kk += 32) {
        __syncthreads();
#pragma unroll
        for (int c = 0; c < 2; ++c) {
            gload_lds16(aBase + (size_t)c * 16 * 768 + kk,
                        &As[(w * 32 + c * 16) * 32]);
            gload_lds16(bBase + (size_t)c * 16 * 768 + kk,
                        &Bs[(w * 32 + c * 16) * 32]);
        }
        __syncthreads();
        bf8v af[4], bg[4];
#pragma unroll
        for (int i = 0; i < 4; ++i) {
            af[i] = *(const bf8v*)&As[(wr * 64 + 16 * i + l15) * 32 + l4 * 8];
            bg[i] = *(const bf8v*)&Bs[(wc * 64 + 16 * i + l15) * 32 + l4 * 8];
        }
#pragma unroll
        for (int i = 0; i < 4; ++i)
#pragma unroll
            for (int j = 0; j < 4; ++j)
                acc[i][j] = __builtin_amdgcn_mfma_f32_16x16x32_bf16(
                    af[i], bg[j], acc[i][j], 0, 0, 0);
    }

#pragma unroll
    for (int j = 0; j < 4; ++j) {
        const int n = col0 + wc * 64 + 16 * j + l15;
        const int s = n / 768;            // block-uniform (768 = 6*128)
        const int rm = n - s * 768;
        const int h = rm >> 6, d = rm & 63;
        const float bv = bias[n];
        if (s == 2) {
            short* vdst = vbT + (size_t)(h * 64 + d) * NTOK;
#pragma unroll
            for (int i = 0; i < 4; ++i) {
                const int m = row0 + wr * 64 + 16 * i + l4 * 4;
                short4 pv;
                pv.x = (short)f2bf(acc[i][j][0] + bv);
                pv.y = (short)f2bf(acc[i][j][1] + bv);
                pv.z = (short)f2bf(acc[i][j][2] + bv);
                pv.w = (short)f2bf(acc[i][j][3] + bv);
                *(short4*)(vdst + m) = pv;
            }
        } else {
            short* dst = (s == 0) ? qbh : kbh;
#pragma unroll
            for (int i = 0; i < 4; ++i) {
                const int m = row0 + wr * 64 + 16 * i + l4 * 4;
#pragma unroll
                for (int r = 0; r < 4; ++r)
                    dst[((size_t)h * NTOK + m + r) * 64 + d] =
                        (short)f2bf(acc[i][j][r] + bv);
            }
        }
    }
}

// ---------------------------------------------------------------------------
// relu: U[j][qw] = sum_d rpwb[j][d] * Q[h][qh*64+qw][d]  (MFMA, per (h,qh))
// then relW[h][qh*64+qw][kw] = LOG2E * U[qw+63-kw][qw]   (LDS gather)
// ---------------------------------------------------------------------------
__global__ __launch_bounds__(256) void relu_kernel(
    const short* __restrict__ qbh, const short* __restrict__ rpwb,
    float* __restrict__ rW)
{
    __shared__ float Us[128][65];
    const int h = blockIdx.x, qh = blockIdx.y;
    const int t = threadIdx.x, w = t >> 6, lane = t & 63;
    const int l15 = lane & 15, l4 = lane >> 4;
    const size_t hB = (size_t)h * NTOK * 64;

    bf8v bq[4][2];
#pragma unroll
    for (int nt = 0; nt < 4; ++nt) {
        const short* qs = qbh + hB + (size_t)(qh * 64 + nt * 16 + l15) * 64;
#pragma unroll
        for (int s = 0; s < 2; ++s)
            bq[nt][s] = *(const bf8v*)(qs + s * 32 + l4 * 8);
    }
    bf8v aw[2][2];
#pragma unroll
    for (int mi = 0; mi < 2; ++mi) {
        const short* as = rpwb + (size_t)((w * 2 + mi) * 16 + l15) * 64;
#pragma unroll
        for (int s = 0; s < 2; ++s)
            aw[mi][s] = *(const bf8v*)(as + s * 32 + l4 * 8);
    }
    f4v U[2][4] = {};
#pragma unroll
    for (int mi = 0; mi < 2; ++mi)
#pragma unroll
        for (int nt = 0; nt < 4; ++nt)
#pragma unroll
            for (int s = 0; s < 2; ++s)
                U[mi][nt] = __builtin_amdgcn_mfma_f32_16x16x32_bf16(
                    aw[mi][s], bq[nt][s], U[mi][nt], 0, 0, 0);
#pragma unroll
    for (int mi = 0; mi < 2; ++mi)
#pragma unroll
        for (int nt = 0; nt < 4; ++nt)
#pragma unroll
            for (int r = 0; r < 4; ++r)
                Us[(w * 2 + mi) * 16 + l4 * 4 + r][nt * 16 + l15] =
                    U[mi][nt][r];
    __syncthreads();
    const int kw = t & 63, q0 = t >> 6;
#pragma unroll
    for (int i = 0; i < 16; ++i) {
        const int q = q0 * 16 + i;
        rW[hB + (size_t)(qh * 64 + q) * 64 + kw] =
            Us[q + 63 - kw][q] * LOG2E;
    }
}

// ---------------------------------------------------------------------------
// Flash attention, S^T formulation, TK=128 (2 sub-tiles/iter), no-max softmax.
// Block = (q-tile 64, head), 4 waves. Each lane owns ONE softmax row (q =
// 16w + lane&15); l is a deferred plain sum (no running max: |logit| << 88,
// and dropping the max subtraction is an exact common rescale of P and l).
// ---------------------------------------------------------------------------
__global__ __launch_bounds__(256, 3) void flash_mfma_kernel(
    const short* __restrict__ qbh, const short* __restrict__ kbh,
    const short* __restrict__ vbT, const float* __restrict__ rW,
    const float* __restrict__ rph, short* __restrict__ aob)
{
    __shared__ __align__(16) short Ks[128][68];   // [tok][d], pad 4 (uniform banks)
    __shared__ __align__(16) short Vt[64][132];   // [d][tok], pad 4
    __shared__ float relHs[64][65];               // [kh][q-local] (log2e-scaled)

    const int t = threadIdx.x;
    const int qt = blockIdx.x, head = blockIdx.y;
    const int row0 = qt * 64;
    const int lane = t & 63, w = t >> 6;
    const int l15 = lane & 15, l4 = lane >> 4;
    const size_t hB = (size_t)head * NTOK * 64;
    const float SC = 0.125f * LOG2E;

    // Q as B-fragments (n = q-row = 16w + l15), k = s*32 + l4*8 + j
    bf8v bQ[2];
    {
        const short* qsrc = qbh + hB + (size_t)(row0 + 16 * w + l15) * 64;
#pragma unroll
        for (int s = 0; s < 2; ++s)
            bQ[s] = *(const bf8v*)(qsrc + s * 32 + l4 * 8);
    }
    // relW preload (LOG2E-scaled): element (q=l15, kw=16nt+4l4+r)
    float rw[4][4];
#pragma unroll
    for (int nt = 0; nt < 4; ++nt)
#pragma unroll
        for (int r = 0; r < 4; ++r)
            rw[nt][r] = rW[hB + (size_t)(row0 + 16 * w + l15) * 64 +
                           nt * 16 + l4 * 4 + r];

    // stage reversed rph slice (x LOG2E) into Ks rows 0..63 for relH GEMM
    {
        const int rr = t >> 2, d0 = (t & 3) * 16;
        const float* src = rph + (size_t)(qt + 63 - rr) * 64 + d0;
        float4 a0 = *(const float4*)(src);
        float4 a1 = *(const float4*)(src + 4);
        float4 a2 = *(const float4*)(src + 8);
        float4 a3 = *(const float4*)(src + 12);
        a0.x *= LOG2E; a0.y *= LOG2E; a0.z *= LOG2E; a0.w *= LOG2E;
        a1.x *= LOG2E; a1.y *= LOG2E; a1.z *= LOG2E; a1.w *= LOG2E;
        a2.x *= LOG2E; a2.y *= LOG2E; a2.z *= LOG2E; a2.w *= LOG2E;
        a3.x *= LOG2E; a3.y *= LOG2E; a3.z *= LOG2E; a3.w *= LOG2E;
        *(bf8v*)&Ks[rr][d0] = pack8(a0, a1);
        *(bf8v*)&Ks[rr][d0 + 8] = pack8(a2, a3);
    }
    // prefetch K/V tile 0 into registers (TK=128: 2 K rows + 64B of V^T each)
    const int sx = t >> 2;            // K token row (and V d-row)
    const int sck = (t & 3) * 16;     // K d-offset (shorts)
    const int scv = (t & 3) * 32;     // V token-offset (shorts)
    const short* kptr = kbh + hB + (size_t)sx * 64 + sck;
    const short* vptr = vbT + ((size_t)head * 64 + sx) * NTOK + scv;
    bf8v kpf[4], vpf[4];
    kpf[0] = *(const bf8v*)(kptr);
    kpf[1] = *(const bf8v*)(kptr + 8);
    kpf[2] = *(const bf8v*)(kptr + 64 * 64);
    kpf[3] = *(const bf8v*)(kptr + 64 * 64 + 8);
    vpf[0] = *(const bf8v*)(vptr);
    vpf[1] = *(const bf8v*)(vptr + 8);
    vpf[2] = *(const bf8v*)(vptr + 16);
    vpf[3] = *(const bf8v*)(vptr + 24);

    __syncthreads();
    // relHs = rph_rev · Q^T  (m = kh, n = q-local)
#pragma unroll
    for (int nt = 0; nt < 4; ++nt) {
        f4v c = {0.f, 0.f, 0.f, 0.f};
#pragma unroll
        for (int s = 0; s < 2; ++s)
            c = __builtin_amdgcn_mfma_f32_16x16x32_bf16(
                *(const bf8v*)&Ks[nt * 16 + l15][s * 32 + l4 * 8], bQ[s], c,
                0, 0, 0);
#pragma unroll
        for (int r = 0; r < 4; ++r)
            relHs[nt * 16 + l4 * 4 + r][16 * w + l15] = c[r];
    }

    f4v O[4] = {{0.f, 0.f, 0.f, 0.f}, {0.f, 0.f, 0.f, 0.f},
                {0.f, 0.f, 0.f, 0.f}, {0.f, 0.f, 0.f, 0.f}};
    float lsum = 0.f;

    const int xsel = ((lane >> 4) & 1) * 32 + l15;      // transform src lane
    const bool lo32 = (lane < 32);

    for (int it = 0; it < 32; ++it) {
        __syncthreads();
        *(bf8v*)&Ks[sx][sck] = kpf[0];
        *(bf8v*)&Ks[sx][sck + 8] = kpf[1];
        *(bf8v*)&Ks[sx + 64][sck] = kpf[2];
        *(bf8v*)&Ks[sx + 64][sck + 8] = kpf[3];
        *(bf8v*)&Vt[sx][scv] = vpf[0];
        *(bf8v*)&Vt[sx][scv + 8] = vpf[1];
        *(bf8v*)&Vt[sx][scv + 16] = vpf[2];
        *(bf8v*)&Vt[sx][scv + 24] = vpf[3];
        {
            const int itn = (it < 31) ? it + 1 : 31;
            const short* kp = kptr + (size_t)itn * 128 * 64;
            const short* vp = vptr + itn * 128;
            kpf[0] = *(const bf8v*)kp;
            kpf[1] = *(const bf8v*)(kp + 8);
            kpf[2] = *(const bf8v*)(kp + 64 * 64);
            kpf[3] = *(const bf8v*)(kp + 64 * 64 + 8);
            vpf[0] = *(const bf8v*)vp;
            vpf[1] = *(const bf8v*)(vp + 8);
            vpf[2] = *(const bf8v*)(vp + 16);
            vpf[3] = *(const bf8v*)(vp + 24);
        }
        __syncthreads();

        // S^T for both sub-tiles (independent chains)
        f4v accA[4] = {{0.f, 0.f, 0.f, 0.f}, {0.f, 0.f, 0.f, 0.f},
                       {0.f, 0.f, 0.f, 0.f}, {0.f, 0.f, 0.f, 0.f}};
        f4v accB[4] = {{0.f, 0.f, 0.f, 0.f}, {0.f, 0.f, 0.f, 0.f},
                       {0.f, 0.f, 0.f, 0.f}, {0.f, 0.f, 0.f, 0.f}};
#pragma unroll
        for (int s = 0; s < 2; ++s)
#pragma unroll
            for (int nt = 0; nt < 4; ++nt) {
                accA[nt] = __builtin_amdgcn_mfma_f32_16x16x32_bf16(
                    *(const bf8v*)&Ks[nt * 16 + l15][s * 32 + l4 * 8], bQ[s],
                    accA[nt], 0, 0, 0);
                accB[nt] = __builtin_amdgcn_mfma_f32_16x16x32_bf16(
                    *(const bf8v*)&Ks[64 + nt * 16 + l15][s * 32 + l4 * 8],
                    bQ[s], accB[nt], 0, 0, 0);
            }

        const float rhA = relHs[2 * it][16 * w + l15];
        const float rhB = relHs[2 * it + 1][16 * w + l15];

        // e = exp2(SC*acc + (rw + rh)); no max subtraction (exact rescale)
        float eA[4][4], eB[4][4];
#pragma unroll
        for (int nt = 0; nt < 4; ++nt)
#pragma unroll
            for (int r = 0; r < 4; ++r) {
                eA[nt][r] = __builtin_amdgcn_exp2f(
                    fmaf(accA[nt][r], SC, rw[nt][r] + rhA));
                eB[nt][r] = __builtin_amdgcn_exp2f(
                    fmaf(accB[nt][r], SC, rw[nt][r] + rhB));
            }
        // deferred l: per-lane partial sum (reduced once in epilogue)
        {
            float sA = ((eA[0][0] + eA[0][1]) + (eA[0][2] + eA[0][3])) +
                       ((eA[1][0] + eA[1][1]) + (eA[1][2] + eA[1][3])) +
                       ((eA[2][0] + eA[2][1]) + (eA[2][2] + eA[2][3])) +
                       ((eA[3][0] + eA[3][1]) + (eA[3][2] + eA[3][3]));
            float sB = ((eB[0][0] + eB[0][1]) + (eB[0][2] + eB[0][3])) +
                       ((eB[1][0] + eB[1][1]) + (eB[1][2] + eB[1][3])) +
                       ((eB[2][0] + eB[2][1]) + (eB[2][2] + eB[2][3])) +
                       ((eB[3][0] + eB[3][1]) + (eB[3][2] + eB[3][3]));
            lsum += sA + sB;
        }

        // pack P, C->A quad-permute transform, PV accumulate — sub-tile A
#pragma unroll
        for (int half = 0; half < 2; ++half) {
            float (*e)[4] = half ? eB : eA;
            unsigned pk[4][2];
#pragma unroll
            for (int nt = 0; nt < 4; ++nt) {
                pk[nt][0] = pkbf(e[nt][1], e[nt][0]);
                pk[nt][1] = pkbf(e[nt][3], e[nt][2]);
            }
            bf8v aP[2];
#pragma unroll
            for (int s = 0; s < 2; ++s) {
                const int x0 = __shfl((int)pk[2 * s][0], xsel);
                const int y0 = __shfl((int)pk[2 * s + 1][0], xsel);
                const int x1 = __shfl((int)pk[2 * s][1], xsel);
                const int y1 = __shfl((int)pk[2 * s + 1][1], xsel);
                const int x2 = __shfl((int)pk[2 * s][0], xsel + 16);
                const int y2 = __shfl((int)pk[2 * s + 1][0], xsel + 16);
                const int x3 = __shfl((int)pk[2 * s][1], xsel + 16);
                const int y3 = __shfl((int)pk[2 * s + 1][1], xsel + 16);
                int4 av;
                av.x = lo32 ? x0 : y0;
                av.y = lo32 ? x1 : y1;
                av.z = lo32 ? x2 : y2;
                av.w = lo32 ? x3 : y3;
                union { int4 i; bf8v v; } u; u.i = av;
                aP[s] = u.v;
            }
#pragma unroll
            for (int s = 0; s < 2; ++s)
#pragma unroll
                for (int nt = 0; nt < 4; ++nt)
                    O[nt] = __builtin_amdgcn_mfma_f32_16x16x32_bf16(
                        aP[s],
                        *(const bf8v*)&Vt[nt * 16 + l15]
                                         [half * 64 + s * 32 + l4 * 8],
                        O[nt], 0, 0, 0);
        }
    }

    // epilogue: reduce l across the 4 token-partitions, normalize, store
    lsum += __shfl_xor(lsum, 16);
    lsum += __shfl_xor(lsum, 32);
    const float linv = 1.0f / lsum;
    float li[4];
#pragma unroll
    for (int r = 0; r < 4; ++r) li[r] = __shfl(linv, 4 * l4 + r);
#pragma unroll
    for (int r = 0; r < 4; ++r) {
        const int row = row0 + 16 * w + l4 * 4 + r;
#pragma unroll
        for (int nt = 0; nt < 4; ++nt)
            aob[(size_t)row * 768 + head * 64 + nt * 16 + l15] =
                (short)f2bf(O[nt][r] * li[r]);
    }
}

// ---------------------------------------------------------------------------
// proj GEMM (MFMA bf16): out[m][n] = aob[m][k] @ pwT[n][k]^T + bias[n] (fp32)
// ---------------------------------------------------------------------------
__global__ __launch_bounds__(256) void proj_mfma_kernel(
    const short* __restrict__ aoh, const short* __restrict__ pwT,
    const float* __restrict__ bias, float* __restrict__ out)
{
    __shared__ __align__(16) short As[128 * 32];
    __shared__ __align__(16) short Bs[128 * 32];
    const int t = threadIdx.x;
    const int w = t >> 6, lane = t & 63;
    const int l15 = lane & 15, l4 = lane >> 4;
    const int wr = w >> 1, wc = w & 1;
    const int row0 = blockIdx.y * 128, col0 = blockIdx.x * 128;
    const int ldr = lane >> 2;
    const int ldk = (lane & 3) * 8;

    f4v acc[4][4] = {};
    const short* aBase = aoh + (size_t)(row0 + w * 32 + ldr) * 768 + ldk;
    const short* bBase = pwT + (size_t)(col0 + w * 32 + ldr) * 768 + ldk;

    for (int kk = 0; kk < 768; kk += 32) {
        __syncthreads();
#pragma unroll
        for (int c = 0; c < 2; ++c) {
            gload_lds16(aBase + (size_t)c * 16 * 768 + kk,
                        &As[(w * 32 + c * 16) * 32]);
            gload_lds16(bBase + (size_t)c * 16 * 768 + kk,
                        &Bs[(w * 32 + c * 16) * 32]);
        }
        __syncthreads();
        bf8v af[4], bg[4];
#pragma unroll
        for (int i = 0; i < 4; ++i) {
            af[i] = *(const bf8v*)&As[(wr * 64 + 16 * i + l15) * 32 + l4 * 8];
            bg[i] = *(const bf8v*)&Bs[(wc * 64 + 16 * i + l15) * 32 + l4 * 8];
        }
#pragma unroll
        for (int i = 0; i < 4; ++i)
#pragma unroll
            for (int j = 0; j < 4; ++j)
                acc[i][j] = __builtin_amdgcn_mfma_f32_16x16x32_bf16(
                    af[i], bg[j], acc[i][j], 0, 0, 0);
    }

#pragma unroll
    for (int j = 0; j < 4; ++j) {
        const int n = col0 + wc * 64 + 16 * j + l15;
        const float bv = bias[n];
#pragma unroll
        for (int i = 0; i < 4; ++i) {
            const int m = row0 + wr * 64 + 16 * i + l4 * 4;
#pragma unroll
            for (int r = 0; r < 4; ++r)
                out[(size_t)(m + r) * 768 + n] = acc[i][j][r] + bv;
        }
    }
}

// ---------------------------------------------------------------------------
extern "C" void kernel_launch(void* const* d_in, const int* in_sizes, int n_in,
                              void* d_out, int out_size, void* d_ws,
                              size_t ws_size, hipStream_t stream)
{
    (void)in_sizes; (void)n_in; (void)out_size; (void)ws_size;
    const float* x    = (const float*)d_in[0];
    const float* qkvw = (const float*)d_in[1];
    const float* qkvb = (const float*)d_in[2];
    const float* pw   = (const float*)d_in[3];
    const float* pb   = (const float*)d_in[4];
    const float* rph  = (const float*)d_in[5];
    const float* rpw  = (const float*)d_in[6];
    float* out = (float*)d_out;

    const size_t S = (size_t)NHEADS * NTOK * 64;  // 3,145,728 (= 4096*768)
    float* rW   = (float*)d_ws;          // S fp32 relW (LOG2E-scaled)
    short* qbh  = (short*)(rW + S);      // S bf16   q  [h][tok][d]
    short* kbh  = qbh + S;               // S bf16   k  [h][tok][d]
    short* vbT  = kbh + S;               // S bf16   v^T [h][d][tok]
    short* xh   = vbT + S;               // S bf16   x  [tok][c]
    short* aob  = xh + S;                // S bf16   attn out [tok][c]
    short* wqkvT = aob + S;              // 2304*768 bf16
    short* pwT  = wqkvT + (size_t)2304 * 768;  // 768*768 bf16
    short* rpwb = pwT + (size_t)768 * 768;     // 128*64 bf16 rel_pos_w
    // total ~48.8 MB

    cvt_kernel<<<dim3(1536), 256, 0, stream>>>(x, xh);
    tcvt_kernel<<<dim3(36, 12), 256, 0, stream>>>(qkvw, wqkvT, 768, 2304);
    tcvt_kernel<<<dim3(12, 12), 256, 0, stream>>>(pw, pwT, 768, 768);
    cvt_rpw_kernel<<<dim3(32), 256, 0, stream>>>(rpw, rpwb);
    qkv_mfma_kernel<<<dim3(18, 32), 256, 0, stream>>>(xh, wqkvT, qkvb,
                                                      qbh, kbh, vbT);
    relu_kernel<<<dim3(NHEADS, 64), 256, 0, stream>>>(qbh, rpwb, rW);
    flash_mfma_kernel<<<dim3(64, NHEADS), 256, 0, stream>>>(qbh, kbh, vbT, rW,
                                                            rph, aob);
    proj_mfma_kernel<<<dim3(6, 32), 256, 0, stream>>>(aob, pwT, pb, out);
}